// Round 2
// baseline (1066.322 us; speedup 1.0000x reference)
//
#include <hip/hip_runtime.h>
#include <hip/hip_cooperative_groups.h>

namespace cg = cooperative_groups;

// Problem constants (match reference)
#define BB 8
#define NN 256
#define FF 64      // F_NODE
#define EE 16      // F_EDGE
#define MM 64      // M_MSG
#define G3 192     // 3*F_NODE
#define OUTD 128
#define ROWS (BB*NN)   // 2048
#define MAXD 64        // padded neighbor cap

__device__ __forceinline__ float sigmoidf_(float x) {
    return 1.0f / (1.0f + __expf(-x));
}

// Agent(device)-scope coherent accesses: MI355X per-XCD L2s are NOT coherent;
// cross-block data (hn double-buffer, out zero-init) must go through the
// device coherence point.
__device__ __forceinline__ void st_agent(float* p, float v) {
    __hip_atomic_store(p, v, __ATOMIC_RELAXED, __HIP_MEMORY_SCOPE_AGENT);
}
__device__ __forceinline__ float ld_agent(const float* p) {
    return __hip_atomic_load((float*)p, __ATOMIC_RELAXED, __HIP_MEMORY_SCOPE_AGENT);
}

// ---------------------------------------------------------------------------
// Fused cooperative MPNN: prep + 3 passes + readout, one launch.
// 1024 blocks x 512 threads, 2 rows/block, 4 blocks/CU.
// Block-local state (compacted edge feats, nbr, deg, h, x) lives in LDS all
// kernel; only hn crosses blocks (agent-scope, grid.sync between passes).
// ---------------------------------------------------------------------------
__global__ __launch_bounds__(512, 8) void k_fused(
    const float* __restrict__ nodes, const float* __restrict__ edges,
    const float* __restrict__ Wmsg, const float* __restrict__ bmsg,
    const float* __restrict__ Wi,   const float* __restrict__ Wh,
    const float* __restrict__ bi,   const float* __restrict__ bh,
    const float* __restrict__ Wg,   const float* __restrict__ bg,
    const float* __restrict__ Wem,  const float* __restrict__ be,
    float* __restrict__ hnA, float* __restrict__ hnB,
    float* __restrict__ out)
{
    cg::grid_group grid = cg::this_grid();
    const int r0  = blockIdx.x * 2;
    const int b   = r0 >> 8;
    const int tid = threadIdx.x;
    const int w   = tid >> 6;
    const int lane = tid & 63;

    __shared__ int   snbr[2][MAXD];
    __shared__ int   sdeg[2];
    __shared__ int   wcnt[8];
    __shared__ float efeat[2][MAXD][EE];   // 8 KB — persists all passes
    __shared__ float part[8][MM];
    __shared__ float smsg[2][MM];
    __shared__ float shold[2][FF];
    __shared__ float sx[2][FF];
    __shared__ float gI[2][3][FF], gH[2][3][FF];
    __shared__ float sg[2][OUTD], se[2][OUTD];

    // zero output accumulator at the coherence point (ordered before the
    // readout atomics by the grid syncs)
    if (blockIdx.x == 0) { st_agent(&out[tid], 0.0f); st_agent(&out[tid + 512], 0.0f); }

    // ---- prep: read own 2 rows of edges (coalesced, once) ----
    const int rr0 = tid >> 8;            // row within block; waves 0-3 -> row 0
    const int j0  = tid & 255;
    const float4* ep = (const float4*)(edges + (((size_t)(r0 + rr0)) * NN + j0) * EE);
    float4 ea = ep[0], eb = ep[1], ec = ep[2], ed = ep[3];
    float s = ea.x+ea.y+ea.z+ea.w + eb.x+eb.y+eb.z+eb.w
            + ec.x+ec.y+ec.z+ec.w + ed.x+ed.y+ed.z+ed.w;
    bool pred = (s != 0.0f);
    unsigned long long m = __ballot(pred);
    if (lane == 0) wcnt[w] = __popcll(m);
    if (tid < 2 * FF) {
        int r = tid >> 6;
        float v = nodes[(size_t)(r0 + r) * FF + (tid & 63)];
        shold[r][tid & 63] = v;          // h init = nodes
        sx[r][tid & 63] = v;
    }
    __syncthreads();

    // ballot-scan compaction: edge feats go straight from regs to LDS
    {
        int wb = rr0 * 4;
        int base = 0;
        #pragma unroll
        for (int q = 0; q < 4; ++q) base += (wb + q < w) ? wcnt[wb + q] : 0;
        int slot = base + __popcll(m & ((1ull << lane) - 1ull));
        if (pred && slot < MAXD) {
            snbr[rr0][slot] = j0;
            float4* dst = (float4*)efeat[rr0][slot];
            dst[0] = ea; dst[1] = eb; dst[2] = ec; dst[3] = ed;
        }
    }
    if (tid == 0) {
        int t0 = wcnt[0]+wcnt[1]+wcnt[2]+wcnt[3];
        int t1 = wcnt[4]+wcnt[5]+wcnt[6]+wcnt[7];
        sdeg[0] = t0 < MAXD ? t0 : MAXD;
        sdeg[1] = t1 < MAXD ? t1 : MAXD;
    }

    // W_msg edge-rows (64..79) column -> registers
    float we[EE];
    #pragma unroll
    for (int k = 0; k < EE; ++k) we[k] = Wmsg[(FF + k) * MM + lane];

    // hn0 = nodes @ W_n + b_msg
    {
        int r = w >> 2, kq = w & 3;
        float p = 0.0f;
        #pragma unroll
        for (int kk = 0; kk < 16; ++kk) {
            int k = kq * 16 + kk;
            p += shold[r][k] * Wmsg[k * MM + lane];
        }
        part[w][lane] = p;
    }
    __syncthreads();
    if (tid < 2 * MM) {
        int r = tid >> 6, tt = tid & 63;
        st_agent(&hnA[(size_t)(r0 + r) * MM + tt],
                 bmsg[tt] + part[r*4+0][tt] + part[r*4+1][tt]
                          + part[r*4+2][tt] + part[r*4+3][tt]);
    }
    __threadfence();
    grid.sync();

    const float* hin = hnA;
    float* hout = hnB;

    for (int pass = 0; pass < 3; ++pass) {
        // ---- message aggregation: waves 0-3 -> row 0, 4-7 -> row 1 ----
        {
            int r = w >> 2, sub = w & 3;
            int d = sdeg[r];
            const float* hb = hin + (size_t)b * NN * MM;
            float acc = 0.0f;
            for (int s2 = sub; s2 < d; s2 += 4) {
                int jj = snbr[r][s2];
                float term = ld_agent(&hb[jj * MM + lane]);
                #pragma unroll
                for (int k = 0; k < EE; ++k) term += efeat[r][s2][k] * we[k];
                acc += fmaxf(term, 0.0f);
            }
            part[w][lane] = acc;
        }
        __syncthreads();
        if ((w & 3) == 0) {
            int r = w >> 2;
            smsg[r][lane] = part[w][lane] + part[w+1][lane]
                          + part[w+2][lane] + part[w+3][lane];
        }
        __syncthreads();

        // ---- GRU gates ----
        if (w < 3) {
            float a0 = bi[w * FF + lane], a1 = a0;
            #pragma unroll 4
            for (int k = 0; k < FF; ++k) {
                float wgt = Wi[k * G3 + w * FF + lane];
                a0 += smsg[0][k] * wgt;
                a1 += smsg[1][k] * wgt;
            }
            gI[0][w][lane] = a0; gI[1][w][lane] = a1;
        } else if (w < 6) {
            int g = w - 3;
            float a0 = bh[g * FF + lane], a1 = a0;
            #pragma unroll 4
            for (int k = 0; k < FF; ++k) {
                float wgt = Wh[k * G3 + g * FF + lane];
                a0 += shold[0][k] * wgt;
                a1 += shold[1][k] * wgt;
            }
            gH[0][g][lane] = a0; gH[1][g][lane] = a1;
        }
        __syncthreads();

        // ---- combine ----
        if (tid < 2 * FF) {
            int r = tid >> 6, tt = tid & 63;
            float rg = sigmoidf_(gI[r][0][tt] + gH[r][0][tt]);
            float zg = sigmoidf_(gI[r][1][tt] + gH[r][1][tt]);
            float ng = tanhf(gI[r][2][tt] + rg * gH[r][2][tt]);
            float hold = shold[r][tt];
            float hnew = (1.0f - zg) * ng + zg * hold;
            if (sdeg[r] == 0) hnew = hold;       // node_mask scatter semantics
            shold[r][tt] = hnew;
        }
        __syncthreads();

        if (pass < 2) {
            // hn for next pass
            {
                int r = w >> 2, kq = w & 3;
                float p = 0.0f;
                #pragma unroll
                for (int kk = 0; kk < 16; ++kk) {
                    int k = kq * 16 + kk;
                    p += shold[r][k] * Wmsg[k * MM + lane];
                }
                part[w][lane] = p;
            }
            __syncthreads();
            if (tid < 2 * MM) {
                int r = tid >> 6, tt = tid & 63;
                st_agent(&hout[(size_t)(r0 + r) * MM + tt],
                         bmsg[tt] + part[r*4+0][tt] + part[r*4+1][tt]
                                  + part[r*4+2][tt] + part[r*4+3][tt]);
            }
            const float* tswap = hin; hin = hout; hout = (float*)tswap;
            __threadfence();
            grid.sync();
        }
    }

    // ---- gated readout ----
    {
        int grp = tid >> 7, o = tid & 127;
        int r = grp >> 1, kind = grp & 1;
        if (kind == 0) {
            float g = bg[o];
            #pragma unroll 4
            for (int k = 0; k < FF; ++k) g += shold[r][k] * Wg[k * OUTD + o];
            #pragma unroll 4
            for (int k = 0; k < FF; ++k) g += sx[r][k] * Wg[(FF + k) * OUTD + o];
            sg[r][o] = g;
        } else {
            float e = be[o];
            #pragma unroll 4
            for (int k = 0; k < FF; ++k) e += shold[r][k] * Wem[k * OUTD + o];
            se[r][o] = e;
        }
    }
    __syncthreads();
    if (tid < OUTD) {
        float v0 = (sdeg[0] != 0) ? sigmoidf_(sg[0][tid]) * se[0][tid] : 0.0f;
        float v1 = (sdeg[1] != 0) ? sigmoidf_(sg[1][tid]) * se[1][tid] : 0.0f;
        atomicAdd(&out[b * OUTD + tid], v0 + v1);
    }
}

// ===========================================================================
// Fallback path: the harness-verified 4-kernel pipeline (146 µs baseline).
// Used only if the cooperative launch is rejected (e.g. under graph capture).
// ===========================================================================
__global__ __launch_bounds__(256) void k_prep(
    const float* __restrict__ nodes, const float* __restrict__ edges,
    const float* __restrict__ Wmsg, const float* __restrict__ bmsg,
    int* __restrict__ deg, int* __restrict__ nbr,
    float* __restrict__ h, float* __restrict__ hn, float* __restrict__ out)
{
    int row = blockIdx.x;
    int tid = threadIdx.x;
    int lane = tid & 63, wv = tid >> 6;
    __shared__ int wcnt[4];
    __shared__ float snode[FF];

    const float4* ep = (const float4*)(edges + (((size_t)row) * NN + tid) * EE);
    float4 a = ep[0], b4 = ep[1], c4 = ep[2], d4 = ep[3];
    float s = a.x+a.y+a.z+a.w + b4.x+b4.y+b4.z+b4.w
            + c4.x+c4.y+c4.z+c4.w + d4.x+d4.y+d4.z+d4.w;
    bool pred = (s != 0.0f);
    unsigned long long m = __ballot(pred);
    if (lane == 0) wcnt[wv] = __popcll(m);
    if (tid < FF) snode[tid] = nodes[(size_t)row * FF + tid];
    __syncthreads();

    int base = 0;
    #pragma unroll
    for (int q = 0; q < 4; ++q) base += (q < wv) ? wcnt[q] : 0;
    int slot = base + __popcll(m & ((1ull << lane) - 1ull));
    if (pred && slot < MAXD) nbr[row * MAXD + slot] = tid;

    if (tid == 0) {
        int tot = wcnt[0] + wcnt[1] + wcnt[2] + wcnt[3];
        deg[row] = (tot < MAXD) ? tot : MAXD;
    }
    if (tid < FF) h[row * FF + tid] = snode[tid];
    if (tid < MM) {
        float acc = bmsg[tid];
        #pragma unroll 8
        for (int k = 0; k < FF; ++k) acc += snode[k] * Wmsg[k * MM + tid];
        hn[row * MM + tid] = acc;
    }
    if (row == 0) {
        #pragma unroll
        for (int i = 0; i < (BB * OUTD) / 256; ++i) out[i * 256 + tid] = 0.0f;
    }
}

__global__ __launch_bounds__(512, 8) void k_pass2(
    const float* __restrict__ edges,
    const float* __restrict__ Wmsg, const float* __restrict__ bmsg,
    const float* __restrict__ Wi, const float* __restrict__ Wh,
    const float* __restrict__ bi, const float* __restrict__ bh,
    const float* __restrict__ nodes,
    const float* __restrict__ Wg, const float* __restrict__ bg,
    const float* __restrict__ We, const float* __restrict__ be,
    const int* __restrict__ deg, const int* __restrict__ nbr,
    const float* __restrict__ hn_in, float* __restrict__ hn_out,
    float* __restrict__ h, float* __restrict__ out, int last)
{
    const int r0  = blockIdx.x * 2;
    const int b   = r0 >> 8;
    const int tid = threadIdx.x;
    const int w   = tid >> 6;
    const int lane = tid & 63;

    __shared__ int   snbr[2][MAXD];
    __shared__ int   sdeg[2];
    __shared__ float efeat[2][MAXD][EE];
    __shared__ float part[8][MM];
    __shared__ float smsg[2][MM];
    __shared__ float shold[2][FF];
    __shared__ float sx[2][FF];
    __shared__ float gI[2][3][FF], gH[2][3][FF];
    __shared__ float shnew[2][FF];
    __shared__ float sg[2][OUTD], se[2][OUTD];

    if (tid < 2) sdeg[tid] = deg[r0 + tid];
    if (tid < 2 * MAXD) {
        int r = tid >> 6;
        snbr[r][tid & 63] = nbr[(r0 + r) * MAXD + (tid & 63)];
    }
    if (tid < 2 * FF) {
        int r = tid >> 6;
        shold[r][tid & 63] = h[(size_t)(r0 + r) * FF + (tid & 63)];
    }
    if (last && tid >= 2 * FF && tid < 4 * FF) {
        int r = (tid >> 6) & 1;
        sx[r][tid & 63] = nodes[(size_t)(r0 + r) * FF + (tid & 63)];
    }

    float we[EE];
    #pragma unroll
    for (int k = 0; k < EE; ++k) we[k] = Wmsg[(FF + k) * MM + lane];
    __syncthreads();

    #pragma unroll
    for (int r = 0; r < 2; ++r) {
        int cnt = sdeg[r] * EE;
        for (int i = tid; i < cnt; i += 512) {
            int slot = i >> 4, k = i & 15;
            efeat[r][slot][k] = edges[(((size_t)(r0 + r)) * NN + snbr[r][slot]) * EE + k];
        }
    }
    __syncthreads();

    {
        int r = w >> 2, sub = w & 3;
        int d = sdeg[r];
        const float* hb = hn_in + (size_t)b * NN * MM;
        float acc = 0.0f;
        for (int s = sub; s < d; s += 4) {
            int j = snbr[r][s];
            float term = hb[j * MM + lane];
            #pragma unroll
            for (int k = 0; k < EE; ++k) term += efeat[r][s][k] * we[k];
            acc += fmaxf(term, 0.0f);
        }
        part[w][lane] = acc;
    }
    __syncthreads();
    if ((w & 3) == 0) {
        int r = w >> 2;
        smsg[r][lane] = part[w][lane] + part[w + 1][lane]
                      + part[w + 2][lane] + part[w + 3][lane];
    }
    __syncthreads();

    if (w < 3) {
        float a0 = bi[w * FF + lane], a1 = a0;
        #pragma unroll 4
        for (int k = 0; k < FF; ++k) {
            float wgt = Wi[k * G3 + w * FF + lane];
            a0 += smsg[0][k] * wgt;
            a1 += smsg[1][k] * wgt;
        }
        gI[0][w][lane] = a0; gI[1][w][lane] = a1;
    } else if (w < 6) {
        int g = w - 3;
        float a0 = bh[g * FF + lane], a1 = a0;
        #pragma unroll 4
        for (int k = 0; k < FF; ++k) {
            float wgt = Wh[k * G3 + g * FF + lane];
            a0 += shold[0][k] * wgt;
            a1 += shold[1][k] * wgt;
        }
        gH[0][g][lane] = a0; gH[1][g][lane] = a1;
    }
    __syncthreads();

    if (tid < 2 * FF) {
        int r = tid >> 6, tt = tid & 63;
        float rr = sigmoidf_(gI[r][0][tt] + gH[r][0][tt]);
        float zz = sigmoidf_(gI[r][1][tt] + gH[r][1][tt]);
        float ng = tanhf(gI[r][2][tt] + rr * gH[r][2][tt]);
        float hold = shold[r][tt];
        float hnew = (1.0f - zz) * ng + zz * hold;
        if (sdeg[r] == 0) hnew = hold;
        shnew[r][tt] = hnew;
        h[(size_t)(r0 + r) * FF + tt] = hnew;
    }
    __syncthreads();

    if (!last) {
        {
            int r = w >> 2, kq = w & 3;
            float p = 0.0f;
            #pragma unroll
            for (int kk = 0; kk < 16; ++kk) {
                int k = kq * 16 + kk;
                p += shnew[r][k] * Wmsg[k * MM + lane];
            }
            part[w][lane] = p;
        }
        __syncthreads();
        if (tid < 2 * MM) {
            int r = tid >> 6, tt = tid & 63;
            hn_out[(size_t)(r0 + r) * MM + tt] = bmsg[tt]
                + part[r*4+0][tt] + part[r*4+1][tt] + part[r*4+2][tt] + part[r*4+3][tt];
        }
    } else {
        int grp = tid >> 7, o = tid & 127;
        int r = grp >> 1, kind = grp & 1;
        if (kind == 0) {
            float g = bg[o];
            #pragma unroll 4
            for (int k = 0; k < FF; ++k) g += shnew[r][k] * Wg[k * OUTD + o];
            #pragma unroll 4
            for (int k = 0; k < FF; ++k) g += sx[r][k] * Wg[(FF + k) * OUTD + o];
            sg[r][o] = g;
        } else {
            float e = be[o];
            #pragma unroll 4
            for (int k = 0; k < FF; ++k) e += shnew[r][k] * We[k * OUTD + o];
            se[r][o] = e;
        }
        __syncthreads();
        if (tid < OUTD) {
            float v0 = (sdeg[0] != 0) ? sigmoidf_(sg[0][tid]) * se[0][tid] : 0.0f;
            float v1 = (sdeg[1] != 0) ? sigmoidf_(sg[1][tid]) * se[1][tid] : 0.0f;
            atomicAdd(&out[b * OUTD + tid], v0 + v1);
        }
    }
}

// ---------------------------------------------------------------------------
extern "C" void kernel_launch(void* const* d_in, const int* in_sizes, int n_in,
                              void* d_out, int out_size, void* d_ws, size_t ws_size,
                              hipStream_t stream) {
    const float* nodes = (const float*)d_in[0];
    const float* edges = (const float*)d_in[1];
    const float* Wmsg  = (const float*)d_in[2];
    const float* bmsg  = (const float*)d_in[3];
    const float* Wi    = (const float*)d_in[4];
    const float* Wh    = (const float*)d_in[5];
    const float* bi    = (const float*)d_in[6];
    const float* bh    = (const float*)d_in[7];
    const float* Wg    = (const float*)d_in[8];
    const float* bg    = (const float*)d_in[9];
    const float* We    = (const float*)d_in[10];
    const float* be    = (const float*)d_in[11];
    float* out = (float*)d_out;
    char* ws = (char*)d_ws;

    // Cooperative path buffers (ws + 0)
    float* hnA = (float*)ws;
    float* hnB = hnA + (size_t)ROWS * MM;

    void* args[] = { (void*)&nodes, (void*)&edges, (void*)&Wmsg, (void*)&bmsg,
                     (void*)&Wi, (void*)&Wh, (void*)&bi, (void*)&bh,
                     (void*)&Wg, (void*)&bg, (void*)&We, (void*)&be,
                     (void*)&hnA, (void*)&hnB, (void*)&out };
    hipError_t err = hipLaunchCooperativeKernel((void*)k_fused, dim3(ROWS/2),
                                                dim3(512), args, 0, stream);
    if (err == hipSuccess) return;

    // Fallback: verified 4-kernel pipeline (disjoint ws region at +4 MB)
    char* ws2 = ws + (4u << 20);
    int*   deg  = (int*)ws2;                                   // 8 KB
    int*   nbr  = (int*)(ws2 + 8192);                          // 512 KB
    float* h    = (float*)(ws2 + 8192 + (size_t)ROWS * MAXD * 4);
    float* fA   = h  + (size_t)ROWS * FF;
    float* fB   = fA + (size_t)ROWS * MM;

    k_prep<<<ROWS, 256, 0, stream>>>(nodes, edges, Wmsg, bmsg, deg, nbr, h, fA, out);
    k_pass2<<<ROWS/2, 512, 0, stream>>>(edges, Wmsg, bmsg, Wi, Wh, bi, bh,
                                        nodes, Wg, bg, We, be, deg, nbr,
                                        fA, fB, h, out, 0);
    k_pass2<<<ROWS/2, 512, 0, stream>>>(edges, Wmsg, bmsg, Wi, Wh, bi, bh,
                                        nodes, Wg, bg, We, be, deg, nbr,
                                        fB, fA, h, out, 0);
    k_pass2<<<ROWS/2, 512, 0, stream>>>(edges, Wmsg, bmsg, Wi, Wh, bi, bh,
                                        nodes, Wg, bg, We, be, deg, nbr,
                                        fA, fB, h, out, 1);
}

// Round 3
// 277.588 us; speedup vs baseline: 3.8414x; 3.8414x over previous
//
#include <hip/hip_runtime.h>

// Problem constants (match reference)
#define BB 8
#define NN 256
#define FF 64      // F_NODE
#define EE 16      // F_EDGE
#define MM 64      // M_MSG
#define G3 192     // 3*F_NODE
#define OUTD 128
#define ROWS (BB*NN)   // 2048
#define MAXD 64        // padded neighbor cap

__device__ __forceinline__ float sigmoidf_(float x) {
    return 1.0f / (1.0f + __expf(-x));
}

// ---------------------------------------------------------------------------
// k_p0: prep + pass 0 fused. 1024 blocks x 512 threads, 2 rows/block.
//  - coalesced full edge read, ballot-scan compaction -> LDS + ws (for p1/p2)
//  - pass-0 message aggregation computes hn0_j = W_n^T nodes_j ON THE FLY
//    (W_n staged in LDS; neighbor node vectors via uniform float4 loads),
//    so no cross-block hn0 exchange is needed -> k_prep launch eliminated.
//  - GRU update, h -> ws, hn1 = W_n^T h1 + b -> ws for pass 1.
// ---------------------------------------------------------------------------
__global__ __launch_bounds__(512, 8) void k_p0(
    const float* __restrict__ nodes, const float* __restrict__ edges,
    const float* __restrict__ Wmsg, const float* __restrict__ bmsg,
    const float* __restrict__ Wi,   const float* __restrict__ Wh,
    const float* __restrict__ bi,   const float* __restrict__ bh,
    int* __restrict__ deg, int* __restrict__ nbr, float* __restrict__ gef,
    float* __restrict__ h, float* __restrict__ hn_out, float* __restrict__ out)
{
    const int r0  = blockIdx.x * 2;
    const int b   = r0 >> 8;
    const int tid = threadIdx.x;
    const int w   = tid >> 6;
    const int lane = tid & 63;

    __shared__ int   snbr[2][MAXD];
    __shared__ int   sdeg[2];
    __shared__ int   wcnt[8];
    __shared__ __align__(16) float efeat[2][MAXD][EE];   // 8 KB
    __shared__ float swm[FF][MM];                        // 16 KB: W_msg node part
    __shared__ float part[8][MM];
    __shared__ float smsg[2][MM];
    __shared__ float shold[2][FF];
    __shared__ float gI[2][3][FF], gH[2][3][FF];

    // zero output accumulator (readout atomics are 2 launches later)
    if (blockIdx.x == 0) { out[tid] = 0.0f; out[tid + 512] = 0.0f; }

    // ---- coalesced edge read (once for the whole pipeline) + detect ----
    const int rr0 = tid >> 8;            // row within block; waves 0-3 -> row 0
    const int j0  = tid & 255;
    const float4* ep = (const float4*)(edges + (((size_t)(r0 + rr0)) * NN + j0) * EE);
    float4 ea = ep[0], eb = ep[1], ec = ep[2], ed = ep[3];
    float s = ea.x+ea.y+ea.z+ea.w + eb.x+eb.y+eb.z+eb.w
            + ec.x+ec.y+ec.z+ec.w + ed.x+ed.y+ed.z+ed.w;
    bool pred = (s != 0.0f);
    unsigned long long m = __ballot(pred);
    if (lane == 0) wcnt[w] = __popcll(m);
    if (tid < 2 * FF) {
        int r = tid >> 6;
        shold[r][tid & 63] = nodes[(size_t)(r0 + r) * FF + (tid & 63)];  // h0 = nodes
    }
    // stage W_msg node-part (rows 0..63) into LDS
    for (int i = tid; i < FF * MM; i += 512) swm[i >> 6][i & 63] = Wmsg[i];
    __syncthreads();

    // ---- ballot-scan compaction: regs -> LDS + ws (for passes 1/2) ----
    {
        int wb = rr0 * 4, base = 0;
        #pragma unroll
        for (int q = 0; q < 4; ++q) base += (wb + q < w) ? wcnt[wb + q] : 0;
        int slot = base + __popcll(m & ((1ull << lane) - 1ull));
        if (pred && slot < MAXD) {
            snbr[rr0][slot] = j0;
            float4* dl = (float4*)efeat[rr0][slot];
            dl[0] = ea; dl[1] = eb; dl[2] = ec; dl[3] = ed;
            nbr[(r0 + rr0) * MAXD + slot] = j0;
            float4* dg = (float4*)(gef + ((size_t)(r0 + rr0) * MAXD + slot) * EE);
            dg[0] = ea; dg[1] = eb; dg[2] = ec; dg[3] = ed;
        }
    }
    if (tid == 0) {
        int t0 = wcnt[0]+wcnt[1]+wcnt[2]+wcnt[3];
        int t1 = wcnt[4]+wcnt[5]+wcnt[6]+wcnt[7];
        sdeg[0] = t0 < MAXD ? t0 : MAXD;
        sdeg[1] = t1 < MAXD ? t1 : MAXD;
        deg[r0] = sdeg[0]; deg[r0 + 1] = sdeg[1];
    }
    float we[EE];
    #pragma unroll
    for (int k = 0; k < EE; ++k) we[k] = Wmsg[(FF + k) * MM + lane];
    float bm = bmsg[lane];
    __syncthreads();

    // ---- pass-0 aggregation, hn0 on the fly (slots processed in pairs) ----
    {
        int r = w >> 2, sub = w & 3;
        int d = sdeg[r];
        const float* nball = nodes + (size_t)b * NN * FF;
        float acc = 0.0f;
        for (int s2 = sub; s2 < d; s2 += 8) {
            int sB = s2 + 4;
            bool h2 = (sB < d);
            int jA = snbr[r][s2];
            int jB = h2 ? snbr[r][sB] : jA;
            const float4* na = (const float4*)(nball + jA * FF);
            const float4* nb4 = (const float4*)(nball + jB * FF);
            float tA = bm, tB = bm;
            #pragma unroll
            for (int k = 0; k < EE; ++k) tA += efeat[r][s2][k] * we[k];
            if (h2) {
                #pragma unroll
                for (int k = 0; k < EE; ++k) tB += efeat[r][sB][k] * we[k];
            }
            #pragma unroll
            for (int kq = 0; kq < 16; ++kq) {
                float4 va = na[kq];
                float4 vb = nb4[kq];
                float w0 = swm[4*kq+0][lane], w1 = swm[4*kq+1][lane];
                float w2 = swm[4*kq+2][lane], w3 = swm[4*kq+3][lane];
                tA += va.x*w0 + va.y*w1 + va.z*w2 + va.w*w3;
                tB += vb.x*w0 + vb.y*w1 + vb.z*w2 + vb.w*w3;
            }
            acc += fmaxf(tA, 0.0f);
            if (h2) acc += fmaxf(tB, 0.0f);
        }
        part[w][lane] = acc;
    }
    __syncthreads();
    if ((w & 3) == 0) {
        int r = w >> 2;
        smsg[r][lane] = part[w][lane] + part[w+1][lane]
                      + part[w+2][lane] + part[w+3][lane];
    }
    __syncthreads();

    // ---- GRU gates ----
    if (w < 3) {
        float a0 = bi[w * FF + lane], a1 = a0;
        #pragma unroll 4
        for (int k = 0; k < FF; ++k) {
            float wgt = Wi[k * G3 + w * FF + lane];
            a0 += smsg[0][k] * wgt;
            a1 += smsg[1][k] * wgt;
        }
        gI[0][w][lane] = a0; gI[1][w][lane] = a1;
    } else if (w < 6) {
        int g = w - 3;
        float a0 = bh[g * FF + lane], a1 = a0;
        #pragma unroll 4
        for (int k = 0; k < FF; ++k) {
            float wgt = Wh[k * G3 + g * FF + lane];
            a0 += shold[0][k] * wgt;
            a1 += shold[1][k] * wgt;
        }
        gH[0][g][lane] = a0; gH[1][g][lane] = a1;
    }
    __syncthreads();

    // ---- combine; h lives in shold, stored to ws for pass 1 ----
    if (tid < 2 * FF) {
        int r = tid >> 6, tt = tid & 63;
        float rg = sigmoidf_(gI[r][0][tt] + gH[r][0][tt]);
        float zg = sigmoidf_(gI[r][1][tt] + gH[r][1][tt]);
        float ng = tanhf(gI[r][2][tt] + rg * gH[r][2][tt]);
        float hold = shold[r][tt];
        float hnew = (1.0f - zg) * ng + zg * hold;
        if (sdeg[r] == 0) hnew = hold;
        shold[r][tt] = hnew;
        h[(size_t)(r0 + r) * FF + tt] = hnew;
    }
    __syncthreads();

    // ---- hn1 = h1 @ W_n + b_msg for pass 1 ----
    {
        int r = w >> 2, kq = w & 3;
        float p = 0.0f;
        #pragma unroll
        for (int kk = 0; kk < 16; ++kk) {
            int k = kq * 16 + kk;
            p += shold[r][k] * swm[k][lane];
        }
        part[w][lane] = p;
    }
    __syncthreads();
    if (tid < 2 * MM) {
        int r = tid >> 6, tt = tid & 63;
        hn_out[(size_t)(r0 + r) * MM + tt] = bmsg[tt]
            + part[r*4+0][tt] + part[r*4+1][tt] + part[r*4+2][tt] + part[r*4+3][tt];
    }
}

// ---------------------------------------------------------------------------
// k_p12: passes 1 & 2. Same as the verified baseline k_pass2, except edge
// features come from the compacted ws buffer (coalesced float4) instead of
// random 64 B gathers from the 33.5 MB edges array.
// ---------------------------------------------------------------------------
__global__ __launch_bounds__(512, 8) void k_p12(
    const float* __restrict__ Wmsg, const float* __restrict__ bmsg,
    const float* __restrict__ Wi, const float* __restrict__ Wh,
    const float* __restrict__ bi, const float* __restrict__ bh,
    const float* __restrict__ nodes,
    const float* __restrict__ Wg, const float* __restrict__ bg,
    const float* __restrict__ We, const float* __restrict__ be,
    const int* __restrict__ deg, const int* __restrict__ nbr,
    const float* __restrict__ gef,
    const float* __restrict__ hn_in, float* __restrict__ hn_out,
    float* __restrict__ h, float* __restrict__ out, int last)
{
    const int r0  = blockIdx.x * 2;
    const int b   = r0 >> 8;
    const int tid = threadIdx.x;
    const int w   = tid >> 6;
    const int lane = tid & 63;

    __shared__ int   snbr[2][MAXD];
    __shared__ int   sdeg[2];
    __shared__ __align__(16) float efeat[2][MAXD][EE];
    __shared__ float part[8][MM];
    __shared__ float smsg[2][MM];
    __shared__ float shold[2][FF];
    __shared__ float sx[2][FF];
    __shared__ float gI[2][3][FF], gH[2][3][FF];
    __shared__ float shnew[2][FF];
    __shared__ float sg[2][OUTD], se[2][OUTD];

    // uniform scalar loads of deg (no LDS round-trip needed before gef load)
    const int d0 = deg[r0], d1 = deg[r0 + 1];
    if (tid == 0) { sdeg[0] = d0; sdeg[1] = d1; }

    if (tid < 2 * MAXD) {
        int r = tid >> 6;
        snbr[r][tid & 63] = nbr[(r0 + r) * MAXD + (tid & 63)];
    }
    if (tid < 2 * FF) {
        int r = tid >> 6;
        shold[r][tid & 63] = h[(size_t)(r0 + r) * FF + (tid & 63)];
    }
    if (last && tid >= 2 * FF && tid < 4 * FF) {
        int r = (tid >> 6) & 1;
        sx[r][tid & 63] = nodes[(size_t)(r0 + r) * FF + (tid & 63)];
    }
    // compacted edge features: coalesced float4
    {
        const float4* g0 = (const float4*)(gef + (size_t)r0 * MAXD * EE);
        const float4* g1 = (const float4*)(gef + (size_t)(r0 + 1) * MAXD * EE);
        for (int i = tid; i < d0 * 4; i += 512) ((float4*)efeat[0])[i] = g0[i];
        for (int i = tid; i < d1 * 4; i += 512) ((float4*)efeat[1])[i] = g1[i];
    }
    float we[EE];
    #pragma unroll
    for (int k = 0; k < EE; ++k) we[k] = Wmsg[(FF + k) * MM + lane];
    __syncthreads();

    // ---- message aggregation: waves 0-3 -> row 0, 4-7 -> row 1 ----
    {
        int r = w >> 2, sub = w & 3;
        int d = sdeg[r];
        const float* hb = hn_in + (size_t)b * NN * MM;
        float acc = 0.0f;
        for (int s = sub; s < d; s += 4) {
            int j = snbr[r][s];
            float term = hb[j * MM + lane];
            #pragma unroll
            for (int k = 0; k < EE; ++k) term += efeat[r][s][k] * we[k];
            acc += fmaxf(term, 0.0f);
        }
        part[w][lane] = acc;
    }
    __syncthreads();
    if ((w & 3) == 0) {
        int r = w >> 2;
        smsg[r][lane] = part[w][lane] + part[w + 1][lane]
                      + part[w + 2][lane] + part[w + 3][lane];
    }
    __syncthreads();

    // ---- GRU gates ----
    if (w < 3) {
        float a0 = bi[w * FF + lane], a1 = a0;
        #pragma unroll 4
        for (int k = 0; k < FF; ++k) {
            float wgt = Wi[k * G3 + w * FF + lane];
            a0 += smsg[0][k] * wgt;
            a1 += smsg[1][k] * wgt;
        }
        gI[0][w][lane] = a0; gI[1][w][lane] = a1;
    } else if (w < 6) {
        int g = w - 3;
        float a0 = bh[g * FF + lane], a1 = a0;
        #pragma unroll 4
        for (int k = 0; k < FF; ++k) {
            float wgt = Wh[k * G3 + g * FF + lane];
            a0 += shold[0][k] * wgt;
            a1 += shold[1][k] * wgt;
        }
        gH[0][g][lane] = a0; gH[1][g][lane] = a1;
    }
    __syncthreads();

    // ---- combine ----
    if (tid < 2 * FF) {
        int r = tid >> 6, tt = tid & 63;
        float rr = sigmoidf_(gI[r][0][tt] + gH[r][0][tt]);
        float zz = sigmoidf_(gI[r][1][tt] + gH[r][1][tt]);
        float ng = tanhf(gI[r][2][tt] + rr * gH[r][2][tt]);
        float hold = shold[r][tt];
        float hnew = (1.0f - zz) * ng + zz * hold;
        if (sdeg[r] == 0) hnew = hold;
        shnew[r][tt] = hnew;
        h[(size_t)(r0 + r) * FF + tt] = hnew;
    }
    __syncthreads();

    if (!last) {
        // hn for next pass
        {
            int r = w >> 2, kq = w & 3;
            float p = 0.0f;
            #pragma unroll
            for (int kk = 0; kk < 16; ++kk) {
                int k = kq * 16 + kk;
                p += shnew[r][k] * Wmsg[k * MM + lane];
            }
            part[w][lane] = p;
        }
        __syncthreads();
        if (tid < 2 * MM) {
            int r = tid >> 6, tt = tid & 63;
            hn_out[(size_t)(r0 + r) * MM + tt] = bmsg[tt]
                + part[r*4+0][tt] + part[r*4+1][tt] + part[r*4+2][tt] + part[r*4+3][tt];
        }
    } else {
        // gated readout: 4 groups of 128 thr = (row, gate-vs-emb)
        int grp = tid >> 7, o = tid & 127;
        int r = grp >> 1, kind = grp & 1;
        if (kind == 0) {
            float g = bg[o];
            #pragma unroll 4
            for (int k = 0; k < FF; ++k) g += shnew[r][k] * Wg[k * OUTD + o];
            #pragma unroll 4
            for (int k = 0; k < FF; ++k) g += sx[r][k] * Wg[(FF + k) * OUTD + o];
            sg[r][o] = g;
        } else {
            float e = be[o];
            #pragma unroll 4
            for (int k = 0; k < FF; ++k) e += shnew[r][k] * We[k * OUTD + o];
            se[r][o] = e;
        }
        __syncthreads();
        if (tid < OUTD) {
            float v0 = (sdeg[0] != 0) ? sigmoidf_(sg[0][tid]) * se[0][tid] : 0.0f;
            float v1 = (sdeg[1] != 0) ? sigmoidf_(sg[1][tid]) * se[1][tid] : 0.0f;
            atomicAdd(&out[b * OUTD + tid], v0 + v1);
        }
    }
}

// ---------------------------------------------------------------------------
extern "C" void kernel_launch(void* const* d_in, const int* in_sizes, int n_in,
                              void* d_out, int out_size, void* d_ws, size_t ws_size,
                              hipStream_t stream) {
    const float* nodes = (const float*)d_in[0];
    const float* edges = (const float*)d_in[1];
    const float* Wmsg  = (const float*)d_in[2];
    const float* bmsg  = (const float*)d_in[3];
    const float* Wi    = (const float*)d_in[4];
    const float* Wh    = (const float*)d_in[5];
    const float* bi    = (const float*)d_in[6];
    const float* bh    = (const float*)d_in[7];
    const float* Wg    = (const float*)d_in[8];
    const float* bg    = (const float*)d_in[9];
    const float* We    = (const float*)d_in[10];
    const float* be    = (const float*)d_in[11];
    float* out = (float*)d_out;
    char* ws = (char*)d_ws;

    int*   deg  = (int*)ws;                                        // 8 KB
    int*   nbr  = (int*)(ws + 8192);                               // 512 KB
    float* gef  = (float*)(ws + 8192 + (size_t)ROWS * MAXD * 4);   // 8 MB
    float* h    = gef + (size_t)ROWS * MAXD * EE;
    float* hnA  = h   + (size_t)ROWS * FF;
    float* hnB  = hnA + (size_t)ROWS * MM;

    // launch 1: prep + pass 0 (hn0 on the fly) -> writes h1, hnA
    k_p0<<<ROWS/2, 512, 0, stream>>>(nodes, edges, Wmsg, bmsg, Wi, Wh, bi, bh,
                                     deg, nbr, gef, h, hnA, out);
    // launch 2: pass 1 -> writes h2, hnB
    k_p12<<<ROWS/2, 512, 0, stream>>>(Wmsg, bmsg, Wi, Wh, bi, bh,
                                      nodes, Wg, bg, We, be, deg, nbr, gef,
                                      hnA, hnB, h, out, 0);
    // launch 3: pass 2 + readout
    k_p12<<<ROWS/2, 512, 0, stream>>>(Wmsg, bmsg, Wi, Wh, bi, bh,
                                      nodes, Wg, bg, We, be, deg, nbr, gef,
                                      hnB, hnA, h, out, 1);
}

// Round 4
// 272.977 us; speedup vs baseline: 3.9063x; 1.0169x over previous
//
#include <hip/hip_runtime.h>

// Problem constants (match reference)
#define BB 8
#define NN 256
#define FF 64      // F_NODE
#define EE 16      // F_EDGE
#define MM 64      // M_MSG
#define G3 192     // 3*F_NODE
#define OUTD 128
#define ROWS (BB*NN)   // 2048
#define MAXD 64        // padded neighbor cap

__device__ __forceinline__ float sigmoidf_(float x) {
    return 1.0f / (1.0f + __expf(-x));
}

// ---------------------------------------------------------------------------
// k_p0: prep + pass 0 fused. 1024 blocks x 512 threads, 2 rows/block.
//  DENSE edge scan: lane i reads float4 #i of the block's contiguous 32 KB
//  edge region (1 KiB per wave per instruction — zero over-fetch). One edge
//  = one 4-lane quad; quad-reduce detects nonzero, ballot+LDS-atomic assigns
//  compacted slots (order arbitrary — summation is order-independent, and
//  edge feats are non-negative so sum==0 <=> all-zero exactly).
//  Pass-0 messages compute hn0_j = W_n^T nodes_j on the fly (no cross-block
//  dependency); GRU update; h and hn1 -> ws for pass 1.
// ---------------------------------------------------------------------------
__global__ __launch_bounds__(512, 8) void k_p0(
    const float* __restrict__ nodes, const float* __restrict__ edges,
    const float* __restrict__ Wmsg, const float* __restrict__ bmsg,
    const float* __restrict__ Wi,   const float* __restrict__ Wh,
    const float* __restrict__ bi,   const float* __restrict__ bh,
    int* __restrict__ deg, int* __restrict__ nbr, float* __restrict__ gef,
    float* __restrict__ h, float* __restrict__ hn_out, float* __restrict__ out)
{
    const int r0  = blockIdx.x * 2;
    const int b   = r0 >> 8;
    const int tid = threadIdx.x;
    const int w   = tid >> 6;
    const int lane = tid & 63;

    __shared__ int   snbr[2][MAXD];
    __shared__ int   sdeg[2];                            // LDS atomic counters
    __shared__ __align__(16) float efeat[2][MAXD][EE];   // 8 KB
    __shared__ float swm[FF][MM];                        // 16 KB: W_msg node part
    __shared__ float part[8][MM];
    __shared__ float smsg[2][MM];
    __shared__ float shold[2][FF];
    __shared__ float gI[2][3][FF], gH[2][3][FF];

    // zero output accumulator (readout atomics are 2 launches later)
    if (blockIdx.x == 0) { out[tid] = 0.0f; out[tid + 512] = 0.0f; }
    if (tid < 2) sdeg[tid] = 0;
    if (tid < 2 * FF) {
        int r = tid >> 6;
        shold[r][tid & 63] = nodes[(size_t)(r0 + r) * FF + (tid & 63)];  // h0
    }
    // stage W_msg node-part (rows 0..63) into LDS
    for (int i = tid; i < FF * MM; i += 512) swm[i >> 6][i & 63] = Wmsg[i];
    __syncthreads();

    // ---- dense coalesced edge scan + quad compaction ----
    // Block's 2 rows = 2048 float4s, contiguous. Iter it: float4 #(it*512+tid).
    const float4* base4 = (const float4*)(edges + (size_t)r0 * NN * EE);
    #pragma unroll
    for (int it = 0; it < 4; ++it) {
        int p  = it * 512 + tid;        // float4 index
        float4 v = base4[p];
        int e  = it * 128 + (tid >> 2); // edge index 0..511
        int rr = e >> 8;                // row within block (uniform per it)
        int j  = e & 255;               // neighbor index
        int q  = lane & 3;              // quarter within edge
        float s4 = v.x + v.y + v.z + v.w;
        s4 += __shfl_xor(s4, 1);
        s4 += __shfl_xor(s4, 2);        // full 16-feat sum in all 4 quad lanes
        bool pred = (s4 != 0.0f);       // exact: feats non-negative
        unsigned long long mk = __ballot(pred && (q == 0));   // quad leaders
        int cnt = __popcll(mk);
        int base = 0;
        if (lane == 0) base = atomicAdd(&sdeg[rr], cnt);
        base = __shfl(base, 0);
        // rank of this quad's leader among the wave's leaders (valid all lanes)
        int slot = base + __popcll(mk & ((1ull << (lane & ~3)) - 1ull));
        if (pred && slot < MAXD) {
            ((float4*)efeat[rr][slot])[q] = v;
            ((float4*)(gef + ((size_t)(r0 + rr) * MAXD + slot) * EE))[q] = v;
            if (q == 0) {
                snbr[rr][slot] = j;
                nbr[(r0 + rr) * MAXD + slot] = j;
            }
        }
    }
    __syncthreads();
    if (tid < 2) {
        int t = sdeg[tid]; t = t < MAXD ? t : MAXD;
        sdeg[tid] = t;
        deg[r0 + tid] = t;
    }
    float we[EE];
    #pragma unroll
    for (int k = 0; k < EE; ++k) we[k] = Wmsg[(FF + k) * MM + lane];
    float bm = bmsg[lane];
    __syncthreads();

    // ---- pass-0 aggregation, hn0 on the fly (slots processed in pairs) ----
    {
        int r = w >> 2, sub = w & 3;
        int d = sdeg[r];
        const float* nball = nodes + (size_t)b * NN * FF;
        float acc = 0.0f;
        for (int s2 = sub; s2 < d; s2 += 8) {
            int sB = s2 + 4;
            bool h2 = (sB < d);
            int jA = snbr[r][s2];
            int jB = h2 ? snbr[r][sB] : jA;
            const float4* na  = (const float4*)(nball + jA * FF);
            const float4* nb4 = (const float4*)(nball + jB * FF);
            float tA = bm, tB = bm;
            #pragma unroll
            for (int k = 0; k < EE; ++k) tA += efeat[r][s2][k] * we[k];
            if (h2) {
                #pragma unroll
                for (int k = 0; k < EE; ++k) tB += efeat[r][sB][k] * we[k];
            }
            #pragma unroll
            for (int kq = 0; kq < 16; ++kq) {
                float4 va = na[kq];
                float4 vb = nb4[kq];
                float w0 = swm[4*kq+0][lane], w1 = swm[4*kq+1][lane];
                float w2 = swm[4*kq+2][lane], w3 = swm[4*kq+3][lane];
                tA += va.x*w0 + va.y*w1 + va.z*w2 + va.w*w3;
                tB += vb.x*w0 + vb.y*w1 + vb.z*w2 + vb.w*w3;
            }
            acc += fmaxf(tA, 0.0f);
            if (h2) acc += fmaxf(tB, 0.0f);
        }
        part[w][lane] = acc;
    }
    __syncthreads();
    if ((w & 3) == 0) {
        int r = w >> 2;
        smsg[r][lane] = part[w][lane] + part[w+1][lane]
                      + part[w+2][lane] + part[w+3][lane];
    }
    __syncthreads();

    // ---- GRU gates ----
    if (w < 3) {
        float a0 = bi[w * FF + lane], a1 = a0;
        #pragma unroll 4
        for (int k = 0; k < FF; ++k) {
            float wgt = Wi[k * G3 + w * FF + lane];
            a0 += smsg[0][k] * wgt;
            a1 += smsg[1][k] * wgt;
        }
        gI[0][w][lane] = a0; gI[1][w][lane] = a1;
    } else if (w < 6) {
        int g = w - 3;
        float a0 = bh[g * FF + lane], a1 = a0;
        #pragma unroll 4
        for (int k = 0; k < FF; ++k) {
            float wgt = Wh[k * G3 + g * FF + lane];
            a0 += shold[0][k] * wgt;
            a1 += shold[1][k] * wgt;
        }
        gH[0][g][lane] = a0; gH[1][g][lane] = a1;
    }
    __syncthreads();

    // ---- combine; h -> ws for pass 1 ----
    if (tid < 2 * FF) {
        int r = tid >> 6, tt = tid & 63;
        float rg = sigmoidf_(gI[r][0][tt] + gH[r][0][tt]);
        float zg = sigmoidf_(gI[r][1][tt] + gH[r][1][tt]);
        float ng = tanhf(gI[r][2][tt] + rg * gH[r][2][tt]);
        float hold = shold[r][tt];
        float hnew = (1.0f - zg) * ng + zg * hold;
        if (sdeg[r] == 0) hnew = hold;
        shold[r][tt] = hnew;
        h[(size_t)(r0 + r) * FF + tt] = hnew;
    }
    __syncthreads();

    // ---- hn1 = h1 @ W_n + b_msg for pass 1 ----
    {
        int r = w >> 2, kq = w & 3;
        float p = 0.0f;
        #pragma unroll
        for (int kk = 0; kk < 16; ++kk) {
            int k = kq * 16 + kk;
            p += shold[r][k] * swm[k][lane];
        }
        part[w][lane] = p;
    }
    __syncthreads();
    if (tid < 2 * MM) {
        int r = tid >> 6, tt = tid & 63;
        hn_out[(size_t)(r0 + r) * MM + tt] = bmsg[tt]
            + part[r*4+0][tt] + part[r*4+1][tt] + part[r*4+2][tt] + part[r*4+3][tt];
    }
}

// ---------------------------------------------------------------------------
// k_p12: passes 1 & 2 (unchanged from verified round-3 version). Edge feats
// come from the compacted ws buffer via dense float4 loads.
// ---------------------------------------------------------------------------
__global__ __launch_bounds__(512, 8) void k_p12(
    const float* __restrict__ Wmsg, const float* __restrict__ bmsg,
    const float* __restrict__ Wi, const float* __restrict__ Wh,
    const float* __restrict__ bi, const float* __restrict__ bh,
    const float* __restrict__ nodes,
    const float* __restrict__ Wg, const float* __restrict__ bg,
    const float* __restrict__ We, const float* __restrict__ be,
    const int* __restrict__ deg, const int* __restrict__ nbr,
    const float* __restrict__ gef,
    const float* __restrict__ hn_in, float* __restrict__ hn_out,
    float* __restrict__ h, float* __restrict__ out, int last)
{
    const int r0  = blockIdx.x * 2;
    const int b   = r0 >> 8;
    const int tid = threadIdx.x;
    const int w   = tid >> 6;
    const int lane = tid & 63;

    __shared__ int   snbr[2][MAXD];
    __shared__ int   sdeg[2];
    __shared__ __align__(16) float efeat[2][MAXD][EE];
    __shared__ float part[8][MM];
    __shared__ float smsg[2][MM];
    __shared__ float shold[2][FF];
    __shared__ float sx[2][FF];
    __shared__ float gI[2][3][FF], gH[2][3][FF];
    __shared__ float shnew[2][FF];
    __shared__ float sg[2][OUTD], se[2][OUTD];

    const int d0 = deg[r0], d1 = deg[r0 + 1];
    if (tid == 0) { sdeg[0] = d0; sdeg[1] = d1; }

    if (tid < 2 * MAXD) {
        int r = tid >> 6;
        snbr[r][tid & 63] = nbr[(r0 + r) * MAXD + (tid & 63)];
    }
    if (tid < 2 * FF) {
        int r = tid >> 6;
        shold[r][tid & 63] = h[(size_t)(r0 + r) * FF + (tid & 63)];
    }
    if (last && tid >= 2 * FF && tid < 4 * FF) {
        int r = (tid >> 6) & 1;
        sx[r][tid & 63] = nodes[(size_t)(r0 + r) * FF + (tid & 63)];
    }
    {
        const float4* g0 = (const float4*)(gef + (size_t)r0 * MAXD * EE);
        const float4* g1 = (const float4*)(gef + (size_t)(r0 + 1) * MAXD * EE);
        for (int i = tid; i < d0 * 4; i += 512) ((float4*)efeat[0])[i] = g0[i];
        for (int i = tid; i < d1 * 4; i += 512) ((float4*)efeat[1])[i] = g1[i];
    }
    float we[EE];
    #pragma unroll
    for (int k = 0; k < EE; ++k) we[k] = Wmsg[(FF + k) * MM + lane];
    __syncthreads();

    // ---- message aggregation ----
    {
        int r = w >> 2, sub = w & 3;
        int d = sdeg[r];
        const float* hb = hn_in + (size_t)b * NN * MM;
        float acc = 0.0f;
        for (int s = sub; s < d; s += 4) {
            int j = snbr[r][s];
            float term = hb[j * MM + lane];
            #pragma unroll
            for (int k = 0; k < EE; ++k) term += efeat[r][s][k] * we[k];
            acc += fmaxf(term, 0.0f);
        }
        part[w][lane] = acc;
    }
    __syncthreads();
    if ((w & 3) == 0) {
        int r = w >> 2;
        smsg[r][lane] = part[w][lane] + part[w + 1][lane]
                      + part[w + 2][lane] + part[w + 3][lane];
    }
    __syncthreads();

    // ---- GRU gates ----
    if (w < 3) {
        float a0 = bi[w * FF + lane], a1 = a0;
        #pragma unroll 4
        for (int k = 0; k < FF; ++k) {
            float wgt = Wi[k * G3 + w * FF + lane];
            a0 += smsg[0][k] * wgt;
            a1 += smsg[1][k] * wgt;
        }
        gI[0][w][lane] = a0; gI[1][w][lane] = a1;
    } else if (w < 6) {
        int g = w - 3;
        float a0 = bh[g * FF + lane], a1 = a0;
        #pragma unroll 4
        for (int k = 0; k < FF; ++k) {
            float wgt = Wh[k * G3 + g * FF + lane];
            a0 += shold[0][k] * wgt;
            a1 += shold[1][k] * wgt;
        }
        gH[0][g][lane] = a0; gH[1][g][lane] = a1;
    }
    __syncthreads();

    // ---- combine ----
    if (tid < 2 * FF) {
        int r = tid >> 6, tt = tid & 63;
        float rr = sigmoidf_(gI[r][0][tt] + gH[r][0][tt]);
        float zz = sigmoidf_(gI[r][1][tt] + gH[r][1][tt]);
        float ng = tanhf(gI[r][2][tt] + rr * gH[r][2][tt]);
        float hold = shold[r][tt];
        float hnew = (1.0f - zz) * ng + zz * hold;
        if (sdeg[r] == 0) hnew = hold;
        shnew[r][tt] = hnew;
        h[(size_t)(r0 + r) * FF + tt] = hnew;
    }
    __syncthreads();

    if (!last) {
        {
            int r = w >> 2, kq = w & 3;
            float p = 0.0f;
            #pragma unroll
            for (int kk = 0; kk < 16; ++kk) {
                int k = kq * 16 + kk;
                p += shnew[r][k] * Wmsg[k * MM + lane];
            }
            part[w][lane] = p;
        }
        __syncthreads();
        if (tid < 2 * MM) {
            int r = tid >> 6, tt = tid & 63;
            hn_out[(size_t)(r0 + r) * MM + tt] = bmsg[tt]
                + part[r*4+0][tt] + part[r*4+1][tt] + part[r*4+2][tt] + part[r*4+3][tt];
        }
    } else {
        int grp = tid >> 7, o = tid & 127;
        int r = grp >> 1, kind = grp & 1;
        if (kind == 0) {
            float g = bg[o];
            #pragma unroll 4
            for (int k = 0; k < FF; ++k) g += shnew[r][k] * Wg[k * OUTD + o];
            #pragma unroll 4
            for (int k = 0; k < FF; ++k) g += sx[r][k] * Wg[(FF + k) * OUTD + o];
            sg[r][o] = g;
        } else {
            float e = be[o];
            #pragma unroll 4
            for (int k = 0; k < FF; ++k) e += shnew[r][k] * We[k * OUTD + o];
            se[r][o] = e;
        }
        __syncthreads();
        if (tid < OUTD) {
            float v0 = (sdeg[0] != 0) ? sigmoidf_(sg[0][tid]) * se[0][tid] : 0.0f;
            float v1 = (sdeg[1] != 0) ? sigmoidf_(sg[1][tid]) * se[1][tid] : 0.0f;
            atomicAdd(&out[b * OUTD + tid], v0 + v1);
        }
    }
}

// ---------------------------------------------------------------------------
extern "C" void kernel_launch(void* const* d_in, const int* in_sizes, int n_in,
                              void* d_out, int out_size, void* d_ws, size_t ws_size,
                              hipStream_t stream) {
    const float* nodes = (const float*)d_in[0];
    const float* edges = (const float*)d_in[1];
    const float* Wmsg  = (const float*)d_in[2];
    const float* bmsg  = (const float*)d_in[3];
    const float* Wi    = (const float*)d_in[4];
    const float* Wh    = (const float*)d_in[5];
    const float* bi    = (const float*)d_in[6];
    const float* bh    = (const float*)d_in[7];
    const float* Wg    = (const float*)d_in[8];
    const float* bg    = (const float*)d_in[9];
    const float* We    = (const float*)d_in[10];
    const float* be    = (const float*)d_in[11];
    float* out = (float*)d_out;
    char* ws = (char*)d_ws;

    int*   deg  = (int*)ws;                                        // 8 KB
    int*   nbr  = (int*)(ws + 8192);                               // 512 KB
    float* gef  = (float*)(ws + 8192 + (size_t)ROWS * MAXD * 4);   // 8 MB
    float* h    = gef + (size_t)ROWS * MAXD * EE;
    float* hnA  = h   + (size_t)ROWS * FF;
    float* hnB  = hnA + (size_t)ROWS * MM;

    // launch 1: prep + pass 0 (hn0 on the fly) -> writes h1, hnA
    k_p0<<<ROWS/2, 512, 0, stream>>>(nodes, edges, Wmsg, bmsg, Wi, Wh, bi, bh,
                                     deg, nbr, gef, h, hnA, out);
    // launch 2: pass 1 -> writes h2, hnB
    k_p12<<<ROWS/2, 512, 0, stream>>>(Wmsg, bmsg, Wi, Wh, bi, bh,
                                      nodes, Wg, bg, We, be, deg, nbr, gef,
                                      hnA, hnB, h, out, 0);
    // launch 3: pass 2 + readout
    k_p12<<<ROWS/2, 512, 0, stream>>>(Wmsg, bmsg, Wi, Wh, bi, bh,
                                      nodes, Wg, bg, We, be, deg, nbr, gef,
                                      hnB, hnA, h, out, 1);
}

// Round 5
// 172.494 us; speedup vs baseline: 6.1818x; 1.5825x over previous
//
#include <hip/hip_runtime.h>

// Problem constants (match reference)
#define BB 8
#define NN 256
#define FF 64      // F_NODE
#define EE 16      // F_EDGE
#define MM 64      // M_MSG
#define G3 192     // 3*F_NODE
#define OUTD 128
#define ROWS (BB*NN)   // 2048
#define MAXD 64        // padded neighbor cap

__device__ __forceinline__ float sigmoidf_(float x) {
    return 1.0f / (1.0f + __expf(-x));
}

// ---------------------------------------------------------------------------
// k_p0: prep + pass 0 fused. 1024 blocks x 512 threads, 2 rows/block.
// __launch_bounds__(512, 4): 4 waves/EU min => <=128 VGPRs. The previous
// (512, 8) capped VGPRs at 64 and SPILLED the aggregation-loop state
// (we[16], va/vb float4s, w0..w3) to scratch -> ~260 MB of TCC scratch
// traffic (FETCH 295 MB invariant across access-pattern rewrites).
// ---------------------------------------------------------------------------
__global__ __launch_bounds__(512, 4) void k_p0(
    const float* __restrict__ nodes, const float* __restrict__ edges,
    const float* __restrict__ Wmsg, const float* __restrict__ bmsg,
    const float* __restrict__ Wi,   const float* __restrict__ Wh,
    const float* __restrict__ bi,   const float* __restrict__ bh,
    int* __restrict__ deg, int* __restrict__ nbr, float* __restrict__ gef,
    float* __restrict__ h, float* __restrict__ hn_out, float* __restrict__ out)
{
    const int r0  = blockIdx.x * 2;
    const int b   = r0 >> 8;
    const int tid = threadIdx.x;
    const int w   = tid >> 6;
    const int lane = tid & 63;

    __shared__ int   snbr[2][MAXD];
    __shared__ int   sdeg[2];                            // LDS atomic counters
    __shared__ __align__(16) float efeat[2][MAXD][EE];   // 8 KB
    __shared__ float swm[FF][MM];                        // 16 KB: W_msg node part
    __shared__ float part[8][MM];
    __shared__ float smsg[2][MM];
    __shared__ float shold[2][FF];
    __shared__ float gI[2][3][FF], gH[2][3][FF];

    // zero output accumulator (readout atomics are 2 launches later)
    if (blockIdx.x == 0) { out[tid] = 0.0f; out[tid + 512] = 0.0f; }
    if (tid < 2) sdeg[tid] = 0;
    if (tid < 2 * FF) {
        int r = tid >> 6;
        shold[r][tid & 63] = nodes[(size_t)(r0 + r) * FF + (tid & 63)];  // h0
    }
    // stage W_msg node-part (rows 0..63) into LDS
    for (int i = tid; i < FF * MM; i += 512) swm[i >> 6][i & 63] = Wmsg[i];
    __syncthreads();

    // ---- dense coalesced edge scan + quad compaction ----
    // Block's 2 rows = 2048 float4s, contiguous. Iter it: float4 #(it*512+tid).
    const float4* base4 = (const float4*)(edges + (size_t)r0 * NN * EE);
    #pragma unroll
    for (int it = 0; it < 4; ++it) {
        int p  = it * 512 + tid;        // float4 index
        float4 v = base4[p];
        int e  = it * 128 + (tid >> 2); // edge index 0..511
        int rr = e >> 8;                // row within block (uniform per it)
        int j  = e & 255;               // neighbor index
        int q  = lane & 3;              // quarter within edge
        float s4 = v.x + v.y + v.z + v.w;
        s4 += __shfl_xor(s4, 1);
        s4 += __shfl_xor(s4, 2);        // full 16-feat sum in all 4 quad lanes
        bool pred = (s4 != 0.0f);       // exact: feats non-negative
        unsigned long long mk = __ballot(pred && (q == 0));   // quad leaders
        int cnt = __popcll(mk);
        int base = 0;
        if (lane == 0) base = atomicAdd(&sdeg[rr], cnt);
        base = __shfl(base, 0);
        // rank of this quad's leader among the wave's leaders (valid all lanes)
        int slot = base + __popcll(mk & ((1ull << (lane & ~3)) - 1ull));
        if (pred && slot < MAXD) {
            ((float4*)efeat[rr][slot])[q] = v;
            ((float4*)(gef + ((size_t)(r0 + rr) * MAXD + slot) * EE))[q] = v;
            if (q == 0) {
                snbr[rr][slot] = j;
                nbr[(r0 + rr) * MAXD + slot] = j;
            }
        }
    }
    __syncthreads();
    if (tid < 2) {
        int t = sdeg[tid]; t = t < MAXD ? t : MAXD;
        sdeg[tid] = t;
        deg[r0 + tid] = t;
    }
    float we[EE];
    #pragma unroll
    for (int k = 0; k < EE; ++k) we[k] = Wmsg[(FF + k) * MM + lane];
    float bm = bmsg[lane];
    __syncthreads();

    // ---- pass-0 aggregation, hn0 on the fly (slots processed in pairs) ----
    {
        int r = w >> 2, sub = w & 3;
        int d = sdeg[r];
        const float* nball = nodes + (size_t)b * NN * FF;
        float acc = 0.0f;
        for (int s2 = sub; s2 < d; s2 += 8) {
            int sB = s2 + 4;
            bool h2 = (sB < d);
            int jA = snbr[r][s2];
            int jB = h2 ? snbr[r][sB] : jA;
            const float4* na  = (const float4*)(nball + jA * FF);
            const float4* nb4 = (const float4*)(nball + jB * FF);
            float tA = bm, tB = bm;
            #pragma unroll
            for (int k = 0; k < EE; ++k) tA += efeat[r][s2][k] * we[k];
            if (h2) {
                #pragma unroll
                for (int k = 0; k < EE; ++k) tB += efeat[r][sB][k] * we[k];
            }
            #pragma unroll
            for (int kq = 0; kq < 16; ++kq) {
                float4 va = na[kq];
                float4 vb = nb4[kq];
                float w0 = swm[4*kq+0][lane], w1 = swm[4*kq+1][lane];
                float w2 = swm[4*kq+2][lane], w3 = swm[4*kq+3][lane];
                tA += va.x*w0 + va.y*w1 + va.z*w2 + va.w*w3;
                tB += vb.x*w0 + vb.y*w1 + vb.z*w2 + vb.w*w3;
            }
            acc += fmaxf(tA, 0.0f);
            if (h2) acc += fmaxf(tB, 0.0f);
        }
        part[w][lane] = acc;
    }
    __syncthreads();
    if ((w & 3) == 0) {
        int r = w >> 2;
        smsg[r][lane] = part[w][lane] + part[w+1][lane]
                      + part[w+2][lane] + part[w+3][lane];
    }
    __syncthreads();

    // ---- GRU gates ----
    if (w < 3) {
        float a0 = bi[w * FF + lane], a1 = a0;
        #pragma unroll 4
        for (int k = 0; k < FF; ++k) {
            float wgt = Wi[k * G3 + w * FF + lane];
            a0 += smsg[0][k] * wgt;
            a1 += smsg[1][k] * wgt;
        }
        gI[0][w][lane] = a0; gI[1][w][lane] = a1;
    } else if (w < 6) {
        int g = w - 3;
        float a0 = bh[g * FF + lane], a1 = a0;
        #pragma unroll 4
        for (int k = 0; k < FF; ++k) {
            float wgt = Wh[k * G3 + g * FF + lane];
            a0 += shold[0][k] * wgt;
            a1 += shold[1][k] * wgt;
        }
        gH[0][g][lane] = a0; gH[1][g][lane] = a1;
    }
    __syncthreads();

    // ---- combine; h -> ws for pass 1 ----
    if (tid < 2 * FF) {
        int r = tid >> 6, tt = tid & 63;
        float rg = sigmoidf_(gI[r][0][tt] + gH[r][0][tt]);
        float zg = sigmoidf_(gI[r][1][tt] + gH[r][1][tt]);
        float ng = tanhf(gI[r][2][tt] + rg * gH[r][2][tt]);
        float hold = shold[r][tt];
        float hnew = (1.0f - zg) * ng + zg * hold;
        if (sdeg[r] == 0) hnew = hold;
        shold[r][tt] = hnew;
        h[(size_t)(r0 + r) * FF + tt] = hnew;
    }
    __syncthreads();

    // ---- hn1 = h1 @ W_n + b_msg for pass 1 ----
    {
        int r = w >> 2, kq = w & 3;
        float p = 0.0f;
        #pragma unroll
        for (int kk = 0; kk < 16; ++kk) {
            int k = kq * 16 + kk;
            p += shold[r][k] * swm[k][lane];
        }
        part[w][lane] = p;
    }
    __syncthreads();
    if (tid < 2 * MM) {
        int r = tid >> 6, tt = tid & 63;
        hn_out[(size_t)(r0 + r) * MM + tt] = bmsg[tt]
            + part[r*4+0][tt] + part[r*4+1][tt] + part[r*4+2][tt] + part[r*4+3][tt];
    }
}

// ---------------------------------------------------------------------------
// k_p12: passes 1 & 2. Same structure as verified baseline; launch bounds
// relaxed to (512,4) to lift the 64-VGPR spill cap (same variable as k_p0,
// separately measurable per-dispatch).
// ---------------------------------------------------------------------------
__global__ __launch_bounds__(512, 4) void k_p12(
    const float* __restrict__ Wmsg, const float* __restrict__ bmsg,
    const float* __restrict__ Wi, const float* __restrict__ Wh,
    const float* __restrict__ bi, const float* __restrict__ bh,
    const float* __restrict__ nodes,
    const float* __restrict__ Wg, const float* __restrict__ bg,
    const float* __restrict__ We, const float* __restrict__ be,
    const int* __restrict__ deg, const int* __restrict__ nbr,
    const float* __restrict__ gef,
    const float* __restrict__ hn_in, float* __restrict__ hn_out,
    float* __restrict__ h, float* __restrict__ out, int last)
{
    const int r0  = blockIdx.x * 2;
    const int b   = r0 >> 8;
    const int tid = threadIdx.x;
    const int w   = tid >> 6;
    const int lane = tid & 63;

    __shared__ int   snbr[2][MAXD];
    __shared__ int   sdeg[2];
    __shared__ __align__(16) float efeat[2][MAXD][EE];
    __shared__ float part[8][MM];
    __shared__ float smsg[2][MM];
    __shared__ float shold[2][FF];
    __shared__ float sx[2][FF];
    __shared__ float gI[2][3][FF], gH[2][3][FF];
    __shared__ float shnew[2][FF];
    __shared__ float sg[2][OUTD], se[2][OUTD];

    const int d0 = deg[r0], d1 = deg[r0 + 1];
    if (tid == 0) { sdeg[0] = d0; sdeg[1] = d1; }

    if (tid < 2 * MAXD) {
        int r = tid >> 6;
        snbr[r][tid & 63] = nbr[(r0 + r) * MAXD + (tid & 63)];
    }
    if (tid < 2 * FF) {
        int r = tid >> 6;
        shold[r][tid & 63] = h[(size_t)(r0 + r) * FF + (tid & 63)];
    }
    if (last && tid >= 2 * FF && tid < 4 * FF) {
        int r = (tid >> 6) & 1;
        sx[r][tid & 63] = nodes[(size_t)(r0 + r) * FF + (tid & 63)];
    }
    {
        const float4* g0 = (const float4*)(gef + (size_t)r0 * MAXD * EE);
        const float4* g1 = (const float4*)(gef + (size_t)(r0 + 1) * MAXD * EE);
        for (int i = tid; i < d0 * 4; i += 512) ((float4*)efeat[0])[i] = g0[i];
        for (int i = tid; i < d1 * 4; i += 512) ((float4*)efeat[1])[i] = g1[i];
    }
    float we[EE];
    #pragma unroll
    for (int k = 0; k < EE; ++k) we[k] = Wmsg[(FF + k) * MM + lane];
    __syncthreads();

    // ---- message aggregation ----
    {
        int r = w >> 2, sub = w & 3;
        int d = sdeg[r];
        const float* hb = hn_in + (size_t)b * NN * MM;
        float acc = 0.0f;
        for (int s = sub; s < d; s += 4) {
            int j = snbr[r][s];
            float term = hb[j * MM + lane];
            #pragma unroll
            for (int k = 0; k < EE; ++k) term += efeat[r][s][k] * we[k];
            acc += fmaxf(term, 0.0f);
        }
        part[w][lane] = acc;
    }
    __syncthreads();
    if ((w & 3) == 0) {
        int r = w >> 2;
        smsg[r][lane] = part[w][lane] + part[w + 1][lane]
                      + part[w + 2][lane] + part[w + 3][lane];
    }
    __syncthreads();

    // ---- GRU gates ----
    if (w < 3) {
        float a0 = bi[w * FF + lane], a1 = a0;
        #pragma unroll 4
        for (int k = 0; k < FF; ++k) {
            float wgt = Wi[k * G3 + w * FF + lane];
            a0 += smsg[0][k] * wgt;
            a1 += smsg[1][k] * wgt;
        }
        gI[0][w][lane] = a0; gI[1][w][lane] = a1;
    } else if (w < 6) {
        int g = w - 3;
        float a0 = bh[g * FF + lane], a1 = a0;
        #pragma unroll 4
        for (int k = 0; k < FF; ++k) {
            float wgt = Wh[k * G3 + g * FF + lane];
            a0 += shold[0][k] * wgt;
            a1 += shold[1][k] * wgt;
        }
        gH[0][g][lane] = a0; gH[1][g][lane] = a1;
    }
    __syncthreads();

    // ---- combine ----
    if (tid < 2 * FF) {
        int r = tid >> 6, tt = tid & 63;
        float rr = sigmoidf_(gI[r][0][tt] + gH[r][0][tt]);
        float zz = sigmoidf_(gI[r][1][tt] + gH[r][1][tt]);
        float ng = tanhf(gI[r][2][tt] + rr * gH[r][2][tt]);
        float hold = shold[r][tt];
        float hnew = (1.0f - zz) * ng + zz * hold;
        if (sdeg[r] == 0) hnew = hold;
        shnew[r][tt] = hnew;
        h[(size_t)(r0 + r) * FF + tt] = hnew;
    }
    __syncthreads();

    if (!last) {
        {
            int r = w >> 2, kq = w & 3;
            float p = 0.0f;
            #pragma unroll
            for (int kk = 0; kk < 16; ++kk) {
                int k = kq * 16 + kk;
                p += shnew[r][k] * Wmsg[k * MM + lane];
            }
            part[w][lane] = p;
        }
        __syncthreads();
        if (tid < 2 * MM) {
            int r = tid >> 6, tt = tid & 63;
            hn_out[(size_t)(r0 + r) * MM + tt] = bmsg[tt]
                + part[r*4+0][tt] + part[r*4+1][tt] + part[r*4+2][tt] + part[r*4+3][tt];
        }
    } else {
        int grp = tid >> 7, o = tid & 127;
        int r = grp >> 1, kind = grp & 1;
        if (kind == 0) {
            float g = bg[o];
            #pragma unroll 4
            for (int k = 0; k < FF; ++k) g += shnew[r][k] * Wg[k * OUTD + o];
            #pragma unroll 4
            for (int k = 0; k < FF; ++k) g += sx[r][k] * Wg[(FF + k) * OUTD + o];
            sg[r][o] = g;
        } else {
            float e = be[o];
            #pragma unroll 4
            for (int k = 0; k < FF; ++k) e += shnew[r][k] * We[k * OUTD + o];
            se[r][o] = e;
        }
        __syncthreads();
        if (tid < OUTD) {
            float v0 = (sdeg[0] != 0) ? sigmoidf_(sg[0][tid]) * se[0][tid] : 0.0f;
            float v1 = (sdeg[1] != 0) ? sigmoidf_(sg[1][tid]) * se[1][tid] : 0.0f;
            atomicAdd(&out[b * OUTD + tid], v0 + v1);
        }
    }
}

// ---------------------------------------------------------------------------
extern "C" void kernel_launch(void* const* d_in, const int* in_sizes, int n_in,
                              void* d_out, int out_size, void* d_ws, size_t ws_size,
                              hipStream_t stream) {
    const float* nodes = (const float*)d_in[0];
    const float* edges = (const float*)d_in[1];
    const float* Wmsg  = (const float*)d_in[2];
    const float* bmsg  = (const float*)d_in[3];
    const float* Wi    = (const float*)d_in[4];
    const float* Wh    = (const float*)d_in[5];
    const float* bi    = (const float*)d_in[6];
    const float* bh    = (const float*)d_in[7];
    const float* Wg    = (const float*)d_in[8];
    const float* bg    = (const float*)d_in[9];
    const float* We    = (const float*)d_in[10];
    const float* be    = (const float*)d_in[11];
    float* out = (float*)d_out;
    char* ws = (char*)d_ws;

    int*   deg  = (int*)ws;                                        // 8 KB
    int*   nbr  = (int*)(ws + 8192);                               // 512 KB
    float* gef  = (float*)(ws + 8192 + (size_t)ROWS * MAXD * 4);   // 8 MB
    float* h    = gef + (size_t)ROWS * MAXD * EE;
    float* hnA  = h   + (size_t)ROWS * FF;
    float* hnB  = hnA + (size_t)ROWS * MM;

    // launch 1: prep + pass 0 (hn0 on the fly) -> writes h1, hnA
    k_p0<<<ROWS/2, 512, 0, stream>>>(nodes, edges, Wmsg, bmsg, Wi, Wh, bi, bh,
                                     deg, nbr, gef, h, hnA, out);
    // launch 2: pass 1 -> writes h2, hnB
    k_p12<<<ROWS/2, 512, 0, stream>>>(Wmsg, bmsg, Wi, Wh, bi, bh,
                                      nodes, Wg, bg, We, be, deg, nbr, gef,
                                      hnA, hnB, h, out, 0);
    // launch 3: pass 2 + readout
    k_p12<<<ROWS/2, 512, 0, stream>>>(Wmsg, bmsg, Wi, Wh, bi, bh,
                                      nodes, Wg, bg, We, be, deg, nbr, gef,
                                      hnB, hnA, h, out, 1);
}

// Round 6
// 145.883 us; speedup vs baseline: 7.3094x; 1.1824x over previous
//
#include <hip/hip_runtime.h>

// Problem constants (match reference)
#define BB 8
#define NN 256
#define FF 64      // F_NODE
#define EE 16      // F_EDGE
#define MM 64      // M_MSG
#define G3 192     // 3*F_NODE
#define OUTD 128
#define ROWS (BB*NN)   // 2048
#define MAXD 64        // padded neighbor cap

__device__ __forceinline__ float sigmoidf_(float x) {
    return 1.0f / (1.0f + __expf(-x));
}

// ---------------------------------------------------------------------------
// k_prep2: 1024 blocks x 512 threads, 2 rows/block.
//  - dense coalesced edge scan (lane i reads float4 #i of the block's
//    contiguous 32 KB edge region) + quad compaction -> gef/nbr/deg (global)
//  - h0 = nodes
//  - hn0 = nodes @ W_n + b_msg computed ONCE PER NODE (not per-edge: the
//    round-5 on-the-fly variant recomputed this ~26x per row and cost
//    k_p0 57 µs; a 4th launch is cheaper than 26x redundant GEMV).
//  - block 0 zeroes out (readout atomics are 3 launches later).
// ---------------------------------------------------------------------------
__global__ __launch_bounds__(512, 4) void k_prep2(
    const float* __restrict__ nodes, const float* __restrict__ edges,
    const float* __restrict__ Wmsg, const float* __restrict__ bmsg,
    int* __restrict__ deg, int* __restrict__ nbr, float* __restrict__ gef,
    float* __restrict__ h, float* __restrict__ hn_out, float* __restrict__ out)
{
    const int r0  = blockIdx.x * 2;
    const int tid = threadIdx.x;
    const int w   = tid >> 6;
    const int lane = tid & 63;

    __shared__ int   sdeg[2];          // LDS atomic counters
    __shared__ float swm[FF][MM];      // 16 KB: W_msg node part
    __shared__ float part[8][MM];      // 2 KB
    __shared__ float shold[2][FF];     // staged node feats

    if (blockIdx.x == 0) { out[tid] = 0.0f; out[tid + 512] = 0.0f; }
    if (tid < 2) sdeg[tid] = 0;
    if (tid < 2 * FF) {
        int r = tid >> 6;
        float v = nodes[(size_t)(r0 + r) * FF + (tid & 63)];
        shold[r][tid & 63] = v;
        h[(size_t)(r0 + r) * FF + (tid & 63)] = v;     // h0 = nodes
    }
    for (int i = tid; i < FF * MM; i += 512) swm[i >> 6][i & 63] = Wmsg[i];
    __syncthreads();

    // ---- dense coalesced edge scan + quad compaction (verified round 4/5) ----
    const float4* base4 = (const float4*)(edges + (size_t)r0 * NN * EE);
    #pragma unroll
    for (int it = 0; it < 4; ++it) {
        int p  = it * 512 + tid;        // float4 index within block region
        float4 v = base4[p];
        int e  = it * 128 + (tid >> 2); // edge index 0..511
        int rr = e >> 8;                // row within block (uniform per it)
        int j  = e & 255;               // neighbor index
        int q  = lane & 3;              // quarter within edge
        float s4 = v.x + v.y + v.z + v.w;
        s4 += __shfl_xor(s4, 1);
        s4 += __shfl_xor(s4, 2);        // full 16-feat sum in all 4 quad lanes
        bool pred = (s4 != 0.0f);       // exact: feats non-negative
        unsigned long long mk = __ballot(pred && (q == 0));   // quad leaders
        int cnt = __popcll(mk);
        int base = 0;
        if (lane == 0) base = atomicAdd(&sdeg[rr], cnt);
        base = __shfl(base, 0);
        int slot = base + __popcll(mk & ((1ull << (lane & ~3)) - 1ull));
        if (pred && slot < MAXD) {
            ((float4*)(gef + ((size_t)(r0 + rr) * MAXD + slot) * EE))[q] = v;
            if (q == 0) nbr[(r0 + rr) * MAXD + slot] = j;
        }
    }
    __syncthreads();
    if (tid < 2) {
        int t = sdeg[tid]; t = t < MAXD ? t : MAXD;
        deg[r0 + tid] = t;
    }

    // ---- hn0 = nodes @ W_n + b_msg (once per node) ----
    {
        int r = w >> 2, kq = w & 3;
        float p = 0.0f;
        #pragma unroll
        for (int kk = 0; kk < 16; ++kk) {
            int k = kq * 16 + kk;
            p += shold[r][k] * swm[k][lane];
        }
        part[w][lane] = p;
    }
    __syncthreads();
    if (tid < 2 * MM) {
        int r = tid >> 6, tt = tid & 63;
        hn_out[(size_t)(r0 + r) * MM + tt] = bmsg[tt]
            + part[r*4+0][tt] + part[r*4+1][tt] + part[r*4+2][tt] + part[r*4+3][tt];
    }
}

// ---------------------------------------------------------------------------
// k_p12: one message pass (verified round-5 version, unchanged). Edge feats
// from compacted ws buffer via dense float4 loads; last pass does readout.
// ---------------------------------------------------------------------------
__global__ __launch_bounds__(512, 4) void k_p12(
    const float* __restrict__ Wmsg, const float* __restrict__ bmsg,
    const float* __restrict__ Wi, const float* __restrict__ Wh,
    const float* __restrict__ bi, const float* __restrict__ bh,
    const float* __restrict__ nodes,
    const float* __restrict__ Wg, const float* __restrict__ bg,
    const float* __restrict__ We, const float* __restrict__ be,
    const int* __restrict__ deg, const int* __restrict__ nbr,
    const float* __restrict__ gef,
    const float* __restrict__ hn_in, float* __restrict__ hn_out,
    float* __restrict__ h, float* __restrict__ out, int last)
{
    const int r0  = blockIdx.x * 2;
    const int b   = r0 >> 8;
    const int tid = threadIdx.x;
    const int w   = tid >> 6;
    const int lane = tid & 63;

    __shared__ int   snbr[2][MAXD];
    __shared__ int   sdeg[2];
    __shared__ __align__(16) float efeat[2][MAXD][EE];
    __shared__ float part[8][MM];
    __shared__ float smsg[2][MM];
    __shared__ float shold[2][FF];
    __shared__ float sx[2][FF];
    __shared__ float gI[2][3][FF], gH[2][3][FF];
    __shared__ float shnew[2][FF];
    __shared__ float sg[2][OUTD], se[2][OUTD];

    const int d0 = deg[r0], d1 = deg[r0 + 1];
    if (tid == 0) { sdeg[0] = d0; sdeg[1] = d1; }

    if (tid < 2 * MAXD) {
        int r = tid >> 6;
        snbr[r][tid & 63] = nbr[(r0 + r) * MAXD + (tid & 63)];
    }
    if (tid < 2 * FF) {
        int r = tid >> 6;
        shold[r][tid & 63] = h[(size_t)(r0 + r) * FF + (tid & 63)];
    }
    if (last && tid >= 2 * FF && tid < 4 * FF) {
        int r = (tid >> 6) & 1;
        sx[r][tid & 63] = nodes[(size_t)(r0 + r) * FF + (tid & 63)];
    }
    {
        const float4* g0 = (const float4*)(gef + (size_t)r0 * MAXD * EE);
        const float4* g1 = (const float4*)(gef + (size_t)(r0 + 1) * MAXD * EE);
        for (int i = tid; i < d0 * 4; i += 512) ((float4*)efeat[0])[i] = g0[i];
        for (int i = tid; i < d1 * 4; i += 512) ((float4*)efeat[1])[i] = g1[i];
    }
    float we[EE];
    #pragma unroll
    for (int k = 0; k < EE; ++k) we[k] = Wmsg[(FF + k) * MM + lane];
    __syncthreads();

    // ---- message aggregation ----
    {
        int r = w >> 2, sub = w & 3;
        int d = sdeg[r];
        const float* hb = hn_in + (size_t)b * NN * MM;
        float acc = 0.0f;
        for (int s = sub; s < d; s += 4) {
            int j = snbr[r][s];
            float term = hb[j * MM + lane];
            #pragma unroll
            for (int k = 0; k < EE; ++k) term += efeat[r][s][k] * we[k];
            acc += fmaxf(term, 0.0f);
        }
        part[w][lane] = acc;
    }
    __syncthreads();
    if ((w & 3) == 0) {
        int r = w >> 2;
        smsg[r][lane] = part[w][lane] + part[w + 1][lane]
                      + part[w + 2][lane] + part[w + 3][lane];
    }
    __syncthreads();

    // ---- GRU gates ----
    if (w < 3) {
        float a0 = bi[w * FF + lane], a1 = a0;
        #pragma unroll 4
        for (int k = 0; k < FF; ++k) {
            float wgt = Wi[k * G3 + w * FF + lane];
            a0 += smsg[0][k] * wgt;
            a1 += smsg[1][k] * wgt;
        }
        gI[0][w][lane] = a0; gI[1][w][lane] = a1;
    } else if (w < 6) {
        int g = w - 3;
        float a0 = bh[g * FF + lane], a1 = a0;
        #pragma unroll 4
        for (int k = 0; k < FF; ++k) {
            float wgt = Wh[k * G3 + g * FF + lane];
            a0 += shold[0][k] * wgt;
            a1 += shold[1][k] * wgt;
        }
        gH[0][g][lane] = a0; gH[1][g][lane] = a1;
    }
    __syncthreads();

    // ---- combine ----
    if (tid < 2 * FF) {
        int r = tid >> 6, tt = tid & 63;
        float rr = sigmoidf_(gI[r][0][tt] + gH[r][0][tt]);
        float zz = sigmoidf_(gI[r][1][tt] + gH[r][1][tt]);
        float ng = tanhf(gI[r][2][tt] + rr * gH[r][2][tt]);
        float hold = shold[r][tt];
        float hnew = (1.0f - zz) * ng + zz * hold;
        if (sdeg[r] == 0) hnew = hold;
        shnew[r][tt] = hnew;
        h[(size_t)(r0 + r) * FF + tt] = hnew;
    }
    __syncthreads();

    if (!last) {
        {
            int r = w >> 2, kq = w & 3;
            float p = 0.0f;
            #pragma unroll
            for (int kk = 0; kk < 16; ++kk) {
                int k = kq * 16 + kk;
                p += shnew[r][k] * Wmsg[k * MM + lane];
            }
            part[w][lane] = p;
        }
        __syncthreads();
        if (tid < 2 * MM) {
            int r = tid >> 6, tt = tid & 63;
            hn_out[(size_t)(r0 + r) * MM + tt] = bmsg[tt]
                + part[r*4+0][tt] + part[r*4+1][tt] + part[r*4+2][tt] + part[r*4+3][tt];
        }
    } else {
        int grp = tid >> 7, o = tid & 127;
        int r = grp >> 1, kind = grp & 1;
        if (kind == 0) {
            float g = bg[o];
            #pragma unroll 4
            for (int k = 0; k < FF; ++k) g += shnew[r][k] * Wg[k * OUTD + o];
            #pragma unroll 4
            for (int k = 0; k < FF; ++k) g += sx[r][k] * Wg[(FF + k) * OUTD + o];
            sg[r][o] = g;
        } else {
            float e = be[o];
            #pragma unroll 4
            for (int k = 0; k < FF; ++k) e += shnew[r][k] * We[k * OUTD + o];
            se[r][o] = e;
        }
        __syncthreads();
        if (tid < OUTD) {
            float v0 = (sdeg[0] != 0) ? sigmoidf_(sg[0][tid]) * se[0][tid] : 0.0f;
            float v1 = (sdeg[1] != 0) ? sigmoidf_(sg[1][tid]) * se[1][tid] : 0.0f;
            atomicAdd(&out[b * OUTD + tid], v0 + v1);
        }
    }
}

// ---------------------------------------------------------------------------
extern "C" void kernel_launch(void* const* d_in, const int* in_sizes, int n_in,
                              void* d_out, int out_size, void* d_ws, size_t ws_size,
                              hipStream_t stream) {
    const float* nodes = (const float*)d_in[0];
    const float* edges = (const float*)d_in[1];
    const float* Wmsg  = (const float*)d_in[2];
    const float* bmsg  = (const float*)d_in[3];
    const float* Wi    = (const float*)d_in[4];
    const float* Wh    = (const float*)d_in[5];
    const float* bi    = (const float*)d_in[6];
    const float* bh    = (const float*)d_in[7];
    const float* Wg    = (const float*)d_in[8];
    const float* bg    = (const float*)d_in[9];
    const float* We    = (const float*)d_in[10];
    const float* be    = (const float*)d_in[11];
    float* out = (float*)d_out;
    char* ws = (char*)d_ws;

    int*   deg  = (int*)ws;                                        // 8 KB
    int*   nbr  = (int*)(ws + 8192);                               // 512 KB
    float* gef  = (float*)(ws + 8192 + (size_t)ROWS * MAXD * 4);   // 8 MB
    float* h    = gef + (size_t)ROWS * MAXD * EE;
    float* hnA  = h   + (size_t)ROWS * FF;
    float* hnB  = hnA + (size_t)ROWS * MM;

    // launch 1: prep (dense scan + compaction, h0, hn0 once per node)
    k_prep2<<<ROWS/2, 512, 0, stream>>>(nodes, edges, Wmsg, bmsg,
                                        deg, nbr, gef, h, hnA, out);
    // launch 2: pass 0  (hnA -> hnB)
    k_p12<<<ROWS/2, 512, 0, stream>>>(Wmsg, bmsg, Wi, Wh, bi, bh,
                                      nodes, Wg, bg, We, be, deg, nbr, gef,
                                      hnA, hnB, h, out, 0);
    // launch 3: pass 1  (hnB -> hnA)
    k_p12<<<ROWS/2, 512, 0, stream>>>(Wmsg, bmsg, Wi, Wh, bi, bh,
                                      nodes, Wg, bg, We, be, deg, nbr, gef,
                                      hnB, hnA, h, out, 0);
    // launch 4: pass 2 + readout (hnA -> unused)
    k_p12<<<ROWS/2, 512, 0, stream>>>(Wmsg, bmsg, Wi, Wh, bi, bh,
                                      nodes, Wg, bg, We, be, deg, nbr, gef,
                                      hnA, hnB, h, out, 1);
}

// Round 7
// 144.664 us; speedup vs baseline: 7.3710x; 1.0084x over previous
//
#include <hip/hip_runtime.h>

// Problem constants (match reference)
#define BB 8
#define NN 256
#define FF 64      // F_NODE
#define EE 16      // F_EDGE
#define MM 64      // M_MSG
#define G3 192     // 3*F_NODE
#define OUTD 128
#define ROWS (BB*NN)   // 2048
#define MAXD 64        // padded neighbor cap

__device__ __forceinline__ float sigmoidf_(float x) {
    return 1.0f / (1.0f + __expf(-x));
}

// ---------------------------------------------------------------------------
// k_prep2: 1024 blocks x 512 threads, 2 rows/block.
// Latency-optimized dense scan: phase 1 issues all 4 coalesced edge loads +
// quad-reduces (independent, deep MLP); phase 2 assigns compacted slots via
// per-quad-leader LDS atomicAdd (no ballot chain — only ~13 nonzero quads
// per iter at 10% density) and stores gef/nbr. hn0 = nodes @ W_n + b once
// per node. h0 is NOT materialized: pass 0 reads nodes directly.
// ---------------------------------------------------------------------------
__global__ __launch_bounds__(512, 4) void k_prep2(
    const float* __restrict__ nodes, const float* __restrict__ edges,
    const float* __restrict__ Wmsg, const float* __restrict__ bmsg,
    int* __restrict__ deg, int* __restrict__ nbr, float* __restrict__ gef,
    float* __restrict__ hn_out, float* __restrict__ out)
{
    const int r0  = blockIdx.x * 2;
    const int tid = threadIdx.x;
    const int w   = tid >> 6;
    const int lane = tid & 63;

    __shared__ int   sdeg[2];          // LDS atomic counters
    __shared__ float swm[FF][MM];      // 16 KB: W_msg node part
    __shared__ float part[8][MM];      // 2 KB
    __shared__ float shold[2][FF];     // staged node feats

    if (blockIdx.x == 0) { out[tid] = 0.0f; out[tid + 512] = 0.0f; }
    if (tid < 2) sdeg[tid] = 0;
    if (tid < 2 * FF) {
        int r = tid >> 6;
        shold[r][tid & 63] = nodes[(size_t)(r0 + r) * FF + (tid & 63)];
    }
    __syncthreads();                   // sdeg=0 visible before scan atomics

    // ---- phase 1: all 4 loads + quad-reduces (independent chains) ----
    const float4* base4 = (const float4*)(edges + (size_t)r0 * NN * EE);
    float4 v[4];
    bool pred[4];
    #pragma unroll
    for (int it = 0; it < 4; ++it) v[it] = base4[it * 512 + tid];
    #pragma unroll
    for (int it = 0; it < 4; ++it) {
        float s4 = v[it].x + v[it].y + v[it].z + v[it].w;
        s4 += __shfl_xor(s4, 1);
        s4 += __shfl_xor(s4, 2);       // full 16-feat sum in all 4 quad lanes
        pred[it] = (s4 != 0.0f);       // exact: feats non-negative
    }

    // ---- phase 2: per-quad-leader slot assignment + stores ----
    const int q = lane & 3;            // quarter within edge
    #pragma unroll
    for (int it = 0; it < 4; ++it) {
        int e  = it * 128 + (tid >> 2); // edge index 0..511
        int rr = e >> 8;                // row within block (uniform per it)
        int j  = e & 255;               // neighbor index
        int slot = 0;
        if (pred[it] && q == 0) slot = atomicAdd(&sdeg[rr], 1);
        slot = __shfl(slot, lane & ~3); // broadcast within quad
        if (pred[it] && slot < MAXD) {
            ((float4*)(gef + ((size_t)(r0 + rr) * MAXD + slot) * EE))[q] = v[it];
            if (q == 0) nbr[(r0 + rr) * MAXD + slot] = j;
        }
    }

    // stage W_msg node-part (rows 0..63) into LDS (overlaps other waves' scans)
    for (int i = tid; i < FF * MM; i += 512) swm[i >> 6][i & 63] = Wmsg[i];
    __syncthreads();                   // swm + final sdeg visible

    if (tid < 2) {
        int t = sdeg[tid]; t = t < MAXD ? t : MAXD;
        deg[r0 + tid] = t;
    }

    // ---- hn0 = nodes @ W_n + b_msg (once per node) ----
    {
        int r = w >> 2, kq = w & 3;
        float p = 0.0f;
        #pragma unroll
        for (int kk = 0; kk < 16; ++kk) {
            int k = kq * 16 + kk;
            p += shold[r][k] * swm[k][lane];
        }
        part[w][lane] = p;
    }
    __syncthreads();
    if (tid < 2 * MM) {
        int r = tid >> 6, tt = tid & 63;
        hn_out[(size_t)(r0 + r) * MM + tt] = bmsg[tt]
            + part[r*4+0][tt] + part[r*4+1][tt] + part[r*4+2][tt] + part[r*4+3][tt];
    }
}

// ---------------------------------------------------------------------------
// k_p12: one message pass (verified round-5/6 structure). hsrc = h-state
// source (nodes for pass 0, h for passes 1/2). efeat read as float4
// (ds_read_b128 broadcast instead of 16x b32). h written only if !last.
// ---------------------------------------------------------------------------
__global__ __launch_bounds__(512, 4) void k_p12(
    const float* __restrict__ Wmsg, const float* __restrict__ bmsg,
    const float* __restrict__ Wi, const float* __restrict__ Wh,
    const float* __restrict__ bi, const float* __restrict__ bh,
    const float* __restrict__ nodes,
    const float* __restrict__ Wg, const float* __restrict__ bg,
    const float* __restrict__ We, const float* __restrict__ be,
    const int* __restrict__ deg, const int* __restrict__ nbr,
    const float* __restrict__ gef, const float* __restrict__ hsrc,
    const float* __restrict__ hn_in, float* __restrict__ hn_out,
    float* __restrict__ h, float* __restrict__ out, int last)
{
    const int r0  = blockIdx.x * 2;
    const int b   = r0 >> 8;
    const int tid = threadIdx.x;
    const int w   = tid >> 6;
    const int lane = tid & 63;

    __shared__ int   snbr[2][MAXD];
    __shared__ int   sdeg[2];
    __shared__ __align__(16) float efeat[2][MAXD][EE];
    __shared__ float part[8][MM];
    __shared__ float smsg[2][MM];
    __shared__ float shold[2][FF];
    __shared__ float sx[2][FF];
    __shared__ float gI[2][3][FF], gH[2][3][FF];
    __shared__ float shnew[2][FF];
    __shared__ float sg[2][OUTD], se[2][OUTD];

    const int d0 = deg[r0], d1 = deg[r0 + 1];
    if (tid == 0) { sdeg[0] = d0; sdeg[1] = d1; }

    if (tid < 2 * MAXD) {
        int r = tid >> 6;
        snbr[r][tid & 63] = nbr[(r0 + r) * MAXD + (tid & 63)];
    }
    if (tid < 2 * FF) {
        int r = tid >> 6;
        shold[r][tid & 63] = hsrc[(size_t)(r0 + r) * FF + (tid & 63)];
    }
    if (last && tid >= 2 * FF && tid < 4 * FF) {
        int r = (tid >> 6) & 1;
        sx[r][tid & 63] = nodes[(size_t)(r0 + r) * FF + (tid & 63)];
    }
    {
        const float4* g0 = (const float4*)(gef + (size_t)r0 * MAXD * EE);
        const float4* g1 = (const float4*)(gef + (size_t)(r0 + 1) * MAXD * EE);
        for (int i = tid; i < d0 * 4; i += 512) ((float4*)efeat[0])[i] = g0[i];
        for (int i = tid; i < d1 * 4; i += 512) ((float4*)efeat[1])[i] = g1[i];
    }
    float we[EE];
    #pragma unroll
    for (int k = 0; k < EE; ++k) we[k] = Wmsg[(FF + k) * MM + lane];
    __syncthreads();

    // ---- message aggregation ----
    {
        int r = w >> 2, sub = w & 3;
        int d = sdeg[r];
        const float* hb = hn_in + (size_t)b * NN * MM;
        float acc = 0.0f;
        for (int s = sub; s < d; s += 4) {
            int j = snbr[r][s];
            float term = hb[j * MM + lane];
            const float4* e4 = (const float4*)efeat[r][s];
            float4 e0 = e4[0], e1 = e4[1], e2 = e4[2], e3 = e4[3];
            term += e0.x*we[0] + e0.y*we[1] + e0.z*we[2] + e0.w*we[3]
                  + e1.x*we[4] + e1.y*we[5] + e1.z*we[6] + e1.w*we[7]
                  + e2.x*we[8] + e2.y*we[9] + e2.z*we[10] + e2.w*we[11]
                  + e3.x*we[12] + e3.y*we[13] + e3.z*we[14] + e3.w*we[15];
            acc += fmaxf(term, 0.0f);
        }
        part[w][lane] = acc;
    }
    __syncthreads();
    if ((w & 3) == 0) {
        int r = w >> 2;
        smsg[r][lane] = part[w][lane] + part[w + 1][lane]
                      + part[w + 2][lane] + part[w + 3][lane];
    }
    __syncthreads();

    // ---- GRU gates ----
    if (w < 3) {
        float a0 = bi[w * FF + lane], a1 = a0;
        #pragma unroll 4
        for (int k = 0; k < FF; ++k) {
            float wgt = Wi[k * G3 + w * FF + lane];
            a0 += smsg[0][k] * wgt;
            a1 += smsg[1][k] * wgt;
        }
        gI[0][w][lane] = a0; gI[1][w][lane] = a1;
    } else if (w < 6) {
        int g = w - 3;
        float a0 = bh[g * FF + lane], a1 = a0;
        #pragma unroll 4
        for (int k = 0; k < FF; ++k) {
            float wgt = Wh[k * G3 + g * FF + lane];
            a0 += shold[0][k] * wgt;
            a1 += shold[1][k] * wgt;
        }
        gH[0][g][lane] = a0; gH[1][g][lane] = a1;
    }
    __syncthreads();

    // ---- combine ----
    if (tid < 2 * FF) {
        int r = tid >> 6, tt = tid & 63;
        float rr = sigmoidf_(gI[r][0][tt] + gH[r][0][tt]);
        float zz = sigmoidf_(gI[r][1][tt] + gH[r][1][tt]);
        float ng = tanhf(gI[r][2][tt] + rr * gH[r][2][tt]);
        float hold = shold[r][tt];
        float hnew = (1.0f - zz) * ng + zz * hold;
        if (sdeg[r] == 0) hnew = hold;
        shnew[r][tt] = hnew;
        if (!last) h[(size_t)(r0 + r) * FF + tt] = hnew;
    }
    __syncthreads();

    if (!last) {
        {
            int r = w >> 2, kq = w & 3;
            float p = 0.0f;
            #pragma unroll
            for (int kk = 0; kk < 16; ++kk) {
                int k = kq * 16 + kk;
                p += shnew[r][k] * Wmsg[k * MM + lane];
            }
            part[w][lane] = p;
        }
        __syncthreads();
        if (tid < 2 * MM) {
            int r = tid >> 6, tt = tid & 63;
            hn_out[(size_t)(r0 + r) * MM + tt] = bmsg[tt]
                + part[r*4+0][tt] + part[r*4+1][tt] + part[r*4+2][tt] + part[r*4+3][tt];
        }
    } else {
        int grp = tid >> 7, o = tid & 127;
        int r = grp >> 1, kind = grp & 1;
        if (kind == 0) {
            float g = bg[o];
            #pragma unroll 4
            for (int k = 0; k < FF; ++k) g += shnew[r][k] * Wg[k * OUTD + o];
            #pragma unroll 4
            for (int k = 0; k < FF; ++k) g += sx[r][k] * Wg[(FF + k) * OUTD + o];
            sg[r][o] = g;
        } else {
            float e = be[o];
            #pragma unroll 4
            for (int k = 0; k < FF; ++k) e += shnew[r][k] * We[k * OUTD + o];
            se[r][o] = e;
        }
        __syncthreads();
        if (tid < OUTD) {
            float v0 = (sdeg[0] != 0) ? sigmoidf_(sg[0][tid]) * se[0][tid] : 0.0f;
            float v1 = (sdeg[1] != 0) ? sigmoidf_(sg[1][tid]) * se[1][tid] : 0.0f;
            atomicAdd(&out[b * OUTD + tid], v0 + v1);
        }
    }
}

// ---------------------------------------------------------------------------
extern "C" void kernel_launch(void* const* d_in, const int* in_sizes, int n_in,
                              void* d_out, int out_size, void* d_ws, size_t ws_size,
                              hipStream_t stream) {
    const float* nodes = (const float*)d_in[0];
    const float* edges = (const float*)d_in[1];
    const float* Wmsg  = (const float*)d_in[2];
    const float* bmsg  = (const float*)d_in[3];
    const float* Wi    = (const float*)d_in[4];
    const float* Wh    = (const float*)d_in[5];
    const float* bi    = (const float*)d_in[6];
    const float* bh    = (const float*)d_in[7];
    const float* Wg    = (const float*)d_in[8];
    const float* bg    = (const float*)d_in[9];
    const float* We    = (const float*)d_in[10];
    const float* be    = (const float*)d_in[11];
    float* out = (float*)d_out;
    char* ws = (char*)d_ws;

    int*   deg  = (int*)ws;                                        // 8 KB
    int*   nbr  = (int*)(ws + 8192);                               // 512 KB
    float* gef  = (float*)(ws + 8192 + (size_t)ROWS * MAXD * 4);   // 8 MB
    float* h    = gef + (size_t)ROWS * MAXD * EE;
    float* hnA  = h   + (size_t)ROWS * FF;
    float* hnB  = hnA + (size_t)ROWS * MM;

    // launch 1: prep (dense scan + compaction + hn0; h0 not materialized)
    k_prep2<<<ROWS/2, 512, 0, stream>>>(nodes, edges, Wmsg, bmsg,
                                        deg, nbr, gef, hnA, out);
    // launch 2: pass 0  (h-state from nodes; hnA -> hnB)
    k_p12<<<ROWS/2, 512, 0, stream>>>(Wmsg, bmsg, Wi, Wh, bi, bh,
                                      nodes, Wg, bg, We, be, deg, nbr, gef,
                                      nodes, hnA, hnB, h, out, 0);
    // launch 3: pass 1  (h-state from h; hnB -> hnA)
    k_p12<<<ROWS/2, 512, 0, stream>>>(Wmsg, bmsg, Wi, Wh, bi, bh,
                                      nodes, Wg, bg, We, be, deg, nbr, gef,
                                      h, hnB, hnA, h, out, 0);
    // launch 4: pass 2 + readout (h-state from h; hnA -> unused)
    k_p12<<<ROWS/2, 512, 0, stream>>>(Wmsg, bmsg, Wi, Wh, bi, bh,
                                      nodes, Wg, bg, We, be, deg, nbr, gef,
                                      h, hnA, hnB, h, out, 1);
}